// Round 1
// baseline (442.246 us; speedup 1.0000x reference)
//
#include <hip/hip_runtime.h>
#include <hip/hip_bf16.h>
#include <math.h>

// GATv2 x2 layers. N=50000, E=800000 (+N self loops), D_in=128, H=4, Hd=32 (HC=128), D_out=64.
// Pipeline: build CSR by dst -> gemm1 (xl1,xr1) -> edge1 (softmax+agg+bias+relu -> h)
//           -> gemm2 (xl2,xr2) -> edge2 -> out.

#define NSLOPE 0.2f

__global__ void zero_counts_kernel(int* __restrict__ counts, int n) {
  int i = blockIdx.x * 256 + threadIdx.x;
  if (i < n) counts[i] = 0;
}

__global__ void count_kernel(const int* __restrict__ dst, int* __restrict__ counts, int E) {
  int e = blockIdx.x * 256 + threadIdx.x;
  if (e < E) atomicAdd(&counts[dst[e]], 1);
}

// Two-level exclusive scan of (counts[i] + 1)  (+1 = self loop)
__global__ __launch_bounds__(256) void scanA_kernel(const int* __restrict__ counts,
                                                    int* __restrict__ offsets,   // partial excl
                                                    int* __restrict__ blockSums, int N) {
  int t = threadIdx.x;
  int lane = t & 63, wv = t >> 6;
  int g0 = blockIdx.x * 1024 + t * 4;
  int v[4];
#pragma unroll
  for (int u = 0; u < 4; u++) {
    int i = g0 + u;
    v[u] = (i < N) ? (counts[i] + 1) : 0;
  }
  int s = v[0] + v[1] + v[2] + v[3];
  int inc = s;
#pragma unroll
  for (int d = 1; d < 64; d <<= 1) {
    int n = __shfl_up(inc, d);
    if (lane >= d) inc += n;
  }
  __shared__ int wsum[4];
  if (lane == 63) wsum[wv] = inc;
  __syncthreads();
  int wprefix = 0;
#pragma unroll
  for (int w = 0; w < 4; w++)
    if (w < wv) wprefix += wsum[w];
  int run = wprefix + inc - s;  // exclusive prefix of this thread's 4-group
#pragma unroll
  for (int u = 0; u < 4; u++) {
    int i = g0 + u;
    if (i < N) offsets[i] = run;
    run += v[u];
  }
  if (t == 255) blockSums[blockIdx.x] = wprefix + inc;
}

__global__ void scanB_kernel(const int* __restrict__ blockSums, int* __restrict__ blockPrefix,
                             int* __restrict__ offsets, int nb, int N) {
  int lane = threadIdx.x;  // 64 threads
  int carry = 0;
  for (int base = 0; base < nb; base += 64) {
    int i = base + lane;
    int v = (i < nb) ? blockSums[i] : 0;
    int inc = v;
#pragma unroll
    for (int d = 1; d < 64; d <<= 1) {
      int n = __shfl_up(inc, d);
      if (lane >= d) inc += n;
    }
    if (i < nb) blockPrefix[i] = carry + inc - v;
    carry += __shfl(inc, 63);
  }
  if (lane == 0) offsets[N] = carry;
}

__global__ void scanC_kernel(const int* __restrict__ blockPrefix, int* __restrict__ offsets,
                             int* __restrict__ cursor, int N) {
  int i = blockIdx.x * 256 + threadIdx.x;
  if (i < N) {
    int v = offsets[i] + blockPrefix[i >> 10];
    offsets[i] = v;
    cursor[i] = v;
  }
}

__global__ void scatter_kernel(const int* __restrict__ srcv, const int* __restrict__ dstv,
                               int* __restrict__ cursor, int* __restrict__ csr_src,
                               int E, int N) {
  int e = blockIdx.x * 256 + threadIdx.x;
  if (e < E) {
    int pos = atomicAdd(&cursor[dstv[e]], 1);
    csr_src[pos] = srcv[e];
  } else if (e < E + N) {
    int i = e - E;
    int pos = atomicAdd(&cursor[i], 1);
    csr_src[pos] = i;  // self loop
  }
}

// gemm1: xl = x@Wl + bl, xr = x@Wr + br.  x:[N,128], W:[128,128].
// Block: 32 rows. 4 waves x 8 rows each; lane covers 4 cols of 256 combined cols.
__global__ __launch_bounds__(256) void gemm1_kernel(const float* __restrict__ x,
    const float* __restrict__ Wl, const float* __restrict__ bl,
    const float* __restrict__ Wr, const float* __restrict__ br,
    float* __restrict__ xl, float* __restrict__ xr, int N) {
  __shared__ float xs[32 * 128];
  int t = threadIdx.x;
  int row0 = blockIdx.x * 32;
  const float4* xg4 = (const float4*)x;
  float4* xs4 = (float4*)xs;
  int b4 = row0 * 32;       // float4 index of block start
  int lim4 = N * 32;
#pragma unroll
  for (int i = 0; i < 4; i++) {
    int idx = t + 256 * i;
    float4 v = make_float4(0.f, 0.f, 0.f, 0.f);
    if (b4 + idx < lim4) v = xg4[b4 + idx];
    xs4[idx] = v;
  }
  __syncthreads();
  int wv = t >> 6, l = t & 63;
  const float* W  = (l < 32) ? Wl : Wr;
  const float* bb = (l < 32) ? bl : br;
  float* outp     = (l < 32) ? xl : xr;
  int c = (l & 31) * 4;
  int rbase = wv * 8;
  float acc[8][4];
#pragma unroll
  for (int r = 0; r < 8; r++)
#pragma unroll
    for (int j = 0; j < 4; j++) acc[r][j] = 0.f;

  for (int k = 0; k < 128; k += 4) {
    float4 w0 = *(const float4*)(W + (k + 0) * 128 + c);
    float4 w1 = *(const float4*)(W + (k + 1) * 128 + c);
    float4 w2 = *(const float4*)(W + (k + 2) * 128 + c);
    float4 w3 = *(const float4*)(W + (k + 3) * 128 + c);
#pragma unroll
    for (int r = 0; r < 8; r++) {
      float4 xv = *(const float4*)(&xs[(rbase + r) * 128 + k]);
      acc[r][0] = fmaf(xv.x, w0.x, fmaf(xv.y, w1.x, fmaf(xv.z, w2.x, fmaf(xv.w, w3.x, acc[r][0]))));
      acc[r][1] = fmaf(xv.x, w0.y, fmaf(xv.y, w1.y, fmaf(xv.z, w2.y, fmaf(xv.w, w3.y, acc[r][1]))));
      acc[r][2] = fmaf(xv.x, w0.z, fmaf(xv.y, w1.z, fmaf(xv.z, w2.z, fmaf(xv.w, w3.z, acc[r][2]))));
      acc[r][3] = fmaf(xv.x, w0.w, fmaf(xv.y, w1.w, fmaf(xv.z, w2.w, fmaf(xv.w, w3.w, acc[r][3]))));
    }
  }
  float4 bv = *(const float4*)(bb + c);
#pragma unroll
  for (int r = 0; r < 8; r++) {
    int row = row0 + rbase + r;
    if (row < N) {
      float4 o = make_float4(acc[r][0] + bv.x, acc[r][1] + bv.y, acc[r][2] + bv.z, acc[r][3] + bv.w);
      *(float4*)(outp + (size_t)row * 128 + c) = o;
    }
  }
}

// gemm2: xl2 = h@Wl2 + bl2, xr2 = h@Wr2 + br2.  h:[N,128], W:[128,64].
// Block: 64 rows. wave wv handles rows [wv*16, wv*16+16): half 0/1 -> 8 rows each.
// Within half-wave, 32 lanes cover 128 combined cols (Wl 64 | Wr 64) as float4.
__global__ __launch_bounds__(256) void gemm2_kernel(const float* __restrict__ h,
    const float* __restrict__ Wl, const float* __restrict__ bl,
    const float* __restrict__ Wr, const float* __restrict__ br,
    float* __restrict__ xl, float* __restrict__ xr, int N) {
  __shared__ float xs[64 * 128];
  int t = threadIdx.x;
  int row0 = blockIdx.x * 64;
  const float4* hg4 = (const float4*)h;
  float4* xs4 = (float4*)xs;
  int b4 = row0 * 32;
  int lim4 = N * 32;
#pragma unroll
  for (int i = 0; i < 8; i++) {
    int idx = t + 256 * i;
    float4 v = make_float4(0.f, 0.f, 0.f, 0.f);
    if (b4 + idx < lim4) v = hg4[b4 + idx];
    xs4[idx] = v;
  }
  __syncthreads();
  int wv = t >> 6, l = t & 63;
  int half = l >> 5, ll = l & 31;
  const float* W  = (ll < 16) ? Wl : Wr;
  const float* bb = (ll < 16) ? bl : br;
  float* outp     = (ll < 16) ? xl : xr;
  int c = (ll & 15) * 4;
  int rbase = wv * 16 + half * 8;
  float acc[8][4];
#pragma unroll
  for (int r = 0; r < 8; r++)
#pragma unroll
    for (int j = 0; j < 4; j++) acc[r][j] = 0.f;

  for (int k = 0; k < 128; k += 4) {
    float4 w0 = *(const float4*)(W + (k + 0) * 64 + c);
    float4 w1 = *(const float4*)(W + (k + 1) * 64 + c);
    float4 w2 = *(const float4*)(W + (k + 2) * 64 + c);
    float4 w3 = *(const float4*)(W + (k + 3) * 64 + c);
#pragma unroll
    for (int r = 0; r < 8; r++) {
      float4 xv = *(const float4*)(&xs[(rbase + r) * 128 + k]);
      acc[r][0] = fmaf(xv.x, w0.x, fmaf(xv.y, w1.x, fmaf(xv.z, w2.x, fmaf(xv.w, w3.x, acc[r][0]))));
      acc[r][1] = fmaf(xv.x, w0.y, fmaf(xv.y, w1.y, fmaf(xv.z, w2.y, fmaf(xv.w, w3.y, acc[r][1]))));
      acc[r][2] = fmaf(xv.x, w0.z, fmaf(xv.y, w1.z, fmaf(xv.z, w2.z, fmaf(xv.w, w3.z, acc[r][2]))));
      acc[r][3] = fmaf(xv.x, w0.w, fmaf(xv.y, w1.w, fmaf(xv.z, w2.w, fmaf(xv.w, w3.w, acc[r][3]))));
    }
  }
  float4 bv = *(const float4*)(bb + c);
#pragma unroll
  for (int r = 0; r < 8; r++) {
    int row = row0 + rbase + r;
    if (row < N) {
      float4 o = make_float4(acc[r][0] + bv.x, acc[r][1] + bv.y, acc[r][2] + bv.z, acc[r][3] + bv.w);
      *(float4*)(outp + (size_t)row * 64 + c) = o;
    }
  }
}

// edge1: one wave per dst node. 128 channels -> 2/lane. head = lane>>4 (16-lane groups).
// h[i][c] = relu(bias[c] + sum_e alpha_e * xl[src_e][c]); alpha = softmax_e(att . leaky(xl[src]+xr[i]))
__global__ __launch_bounds__(256) void edge1_kernel(
    const float* __restrict__ xl, const float* __restrict__ xr,
    const float* __restrict__ att, const float* __restrict__ bias,
    const int* __restrict__ offsets, const int* __restrict__ csr_src,
    float* __restrict__ h, int N) {
  int node = blockIdx.x * 4 + (threadIdx.x >> 6);
  if (node >= N) return;
  int lane = threadIdx.x & 63;
  int c = lane * 2;
  float2 xri = *(const float2*)(xr + (size_t)node * 128 + c);
  float2 at  = *(const float2*)(att + c);
  int s0 = __builtin_amdgcn_readfirstlane(offsets[node]);
  int s1 = __builtin_amdgcn_readfirstlane(offsets[node + 1]);
  float m = -1e30f, l = 0.f, a0 = 0.f, a1 = 0.f;
  for (int e = s0; e < s1; e++) {
    int j = __builtin_amdgcn_readfirstlane(csr_src[e]);
    float2 msg = *(const float2*)(xl + (size_t)j * 128 + c);
    float e0 = msg.x + xri.x; e0 = fmaxf(e0, NSLOPE * e0);
    float e1 = msg.y + xri.y; e1 = fmaxf(e1, NSLOPE * e1);
    float p = fmaf(e0, at.x, e1 * at.y);
    // reduce over the 16-lane head group
    p += __shfl_xor(p, 1, 16);
    p += __shfl_xor(p, 2, 16);
    p += __shfl_xor(p, 4, 16);
    p += __shfl_xor(p, 8, 16);
    float nm = fmaxf(m, p);
    float scale = __expf(m - nm);
    float pe = __expf(p - nm);
    l  = fmaf(l, scale, pe);
    a0 = fmaf(a0, scale, pe * msg.x);
    a1 = fmaf(a1, scale, pe * msg.y);
    m = nm;
  }
  float inv = 1.f / l;
  float2 bb = *(const float2*)(bias + c);
  float o0 = fmaxf(fmaf(a0, inv, bb.x), 0.f);
  float o1 = fmaxf(fmaf(a1, inv, bb.y), 0.f);
  *(float2*)(h + (size_t)node * 128 + c) = make_float2(o0, o1);
}

// edge2: one wave per dst node. 64 channels -> 1/lane, 1 head (full-wave reduce).
__global__ __launch_bounds__(256) void edge2_kernel(
    const float* __restrict__ xl, const float* __restrict__ xr,
    const float* __restrict__ att, const float* __restrict__ bias,
    const int* __restrict__ offsets, const int* __restrict__ csr_src,
    float* __restrict__ out, int N) {
  int node = blockIdx.x * 4 + (threadIdx.x >> 6);
  if (node >= N) return;
  int lane = threadIdx.x & 63;
  float xri = xr[(size_t)node * 64 + lane];
  float at  = att[lane];
  int s0 = __builtin_amdgcn_readfirstlane(offsets[node]);
  int s1 = __builtin_amdgcn_readfirstlane(offsets[node + 1]);
  float m = -1e30f, l = 0.f, a = 0.f;
  for (int e = s0; e < s1; e++) {
    int j = __builtin_amdgcn_readfirstlane(csr_src[e]);
    float msg = xl[(size_t)j * 64 + lane];
    float ee = msg + xri; ee = fmaxf(ee, NSLOPE * ee);
    float p = ee * at;
    p += __shfl_xor(p, 1);
    p += __shfl_xor(p, 2);
    p += __shfl_xor(p, 4);
    p += __shfl_xor(p, 8);
    p += __shfl_xor(p, 16);
    p += __shfl_xor(p, 32);
    float nm = fmaxf(m, p);
    float scale = __expf(m - nm);
    float pe = __expf(p - nm);
    l = fmaf(l, scale, pe);
    a = fmaf(a, scale, pe * msg);
    m = nm;
  }
  out[(size_t)node * 64 + lane] = fmaf(a, 1.f / l, bias[lane]);
}

extern "C" void kernel_launch(void* const* d_in, const int* in_sizes, int n_in,
                              void* d_out, int out_size, void* d_ws, size_t ws_size,
                              hipStream_t stream) {
  const float* x    = (const float*)d_in[0];
  const int*   ei   = (const int*)d_in[1];
  const float* Wl1  = (const float*)d_in[2];
  const float* bl1  = (const float*)d_in[3];
  const float* Wr1  = (const float*)d_in[4];
  const float* br1  = (const float*)d_in[5];
  const float* att1 = (const float*)d_in[6];
  const float* bias1= (const float*)d_in[7];
  const float* Wl2  = (const float*)d_in[8];
  const float* bl2  = (const float*)d_in[9];
  const float* Wr2  = (const float*)d_in[10];
  const float* br2  = (const float*)d_in[11];
  const float* att2 = (const float*)d_in[12];
  const float* bias2= (const float*)d_in[13];
  float* out = (float*)d_out;

  const int N = in_sizes[0] / 128;
  const int E = in_sizes[1] / 2;
  const int Etot = E + N;
  const int* srcv = ei;
  const int* dstv = ei + E;

  char* ws = (char*)d_ws;
  size_t off = 0;
  auto alloc = [&](size_t bytes) -> void* {
    void* p = ws + off;
    off = (off + bytes + 255) & ~(size_t)255;
    return p;
  };
  int* offsets     = (int*)alloc((size_t)(N + 1) * 4);
  int* cursor      = (int*)alloc((size_t)N * 4);
  int* counts      = (int*)alloc((size_t)N * 4);
  int* blockSums   = (int*)alloc(256 * 4);
  int* blockPrefix = (int*)alloc(256 * 4);
  int* csr_src     = (int*)alloc((size_t)Etot * 4);
  float* xl1 = (float*)alloc((size_t)N * 128 * 4);
  float* xr1 = (float*)alloc((size_t)N * 128 * 4);
  float* hbuf= (float*)alloc((size_t)N * 128 * 4);
  float* xl2 = xl1;  // reuse (xl1/xr1 dead after edge1)
  float* xr2 = xr1;
  (void)ws_size; (void)n_in; (void)out_size;

  int nb = (N + 1023) / 1024;

  zero_counts_kernel<<<(N + 255) / 256, 256, 0, stream>>>(counts, N);
  count_kernel<<<(E + 255) / 256, 256, 0, stream>>>(dstv, counts, E);
  scanA_kernel<<<nb, 256, 0, stream>>>(counts, offsets, blockSums, N);
  scanB_kernel<<<1, 64, 0, stream>>>(blockSums, blockPrefix, offsets, nb, N);
  scanC_kernel<<<(N + 255) / 256, 256, 0, stream>>>(blockPrefix, offsets, cursor, N);
  scatter_kernel<<<(Etot + 255) / 256, 256, 0, stream>>>(srcv, dstv, cursor, csr_src, E, N);
  gemm1_kernel<<<(N + 31) / 32, 256, 0, stream>>>(x, Wl1, bl1, Wr1, br1, xl1, xr1, N);
  edge1_kernel<<<(N + 3) / 4, 256, 0, stream>>>(xl1, xr1, att1, bias1, offsets, csr_src, hbuf, N);
  gemm2_kernel<<<(N + 63) / 64, 256, 0, stream>>>(hbuf, Wl2, bl2, Wr2, br2, xl2, xr2, N);
  edge2_kernel<<<(N + 3) / 4, 256, 0, stream>>>(xl2, xr2, att2, bias2, offsets, csr_src, out, N);
}

// Round 2
// 393.805 us; speedup vs baseline: 1.1230x; 1.1230x over previous
//
#include <hip/hip_runtime.h>
#include <hip/hip_bf16.h>
#include <math.h>

// GATv2 x2 layers. N=50000, E=800000 (+N self loops), D_in=128, H=4, Hd=32 (HC=128), D_out=64.
// Pipeline: build CSR by dst -> gemm1 (xl1,xr1) -> edge1 (softmax+agg+bias+relu -> h)
//           -> gemm2 (xl2,xr2) -> edge2 -> out.
// R1: edge kernels unrolled x4 with batched online-softmax update (latency-bound chain fix).

#define NSLOPE 0.2f

__global__ void zero_counts_kernel(int* __restrict__ counts, int n) {
  int i = blockIdx.x * 256 + threadIdx.x;
  if (i < n) counts[i] = 0;
}

__global__ void count_kernel(const int* __restrict__ dst, int* __restrict__ counts, int E) {
  int e = blockIdx.x * 256 + threadIdx.x;
  if (e < E) atomicAdd(&counts[dst[e]], 1);
}

// Two-level exclusive scan of (counts[i] + 1)  (+1 = self loop)
__global__ __launch_bounds__(256) void scanA_kernel(const int* __restrict__ counts,
                                                    int* __restrict__ offsets,   // partial excl
                                                    int* __restrict__ blockSums, int N) {
  int t = threadIdx.x;
  int lane = t & 63, wv = t >> 6;
  int g0 = blockIdx.x * 1024 + t * 4;
  int v[4];
#pragma unroll
  for (int u = 0; u < 4; u++) {
    int i = g0 + u;
    v[u] = (i < N) ? (counts[i] + 1) : 0;
  }
  int s = v[0] + v[1] + v[2] + v[3];
  int inc = s;
#pragma unroll
  for (int d = 1; d < 64; d <<= 1) {
    int n = __shfl_up(inc, d);
    if (lane >= d) inc += n;
  }
  __shared__ int wsum[4];
  if (lane == 63) wsum[wv] = inc;
  __syncthreads();
  int wprefix = 0;
#pragma unroll
  for (int w = 0; w < 4; w++)
    if (w < wv) wprefix += wsum[w];
  int run = wprefix + inc - s;  // exclusive prefix of this thread's 4-group
#pragma unroll
  for (int u = 0; u < 4; u++) {
    int i = g0 + u;
    if (i < N) offsets[i] = run;
    run += v[u];
  }
  if (t == 255) blockSums[blockIdx.x] = wprefix + inc;
}

__global__ void scanB_kernel(const int* __restrict__ blockSums, int* __restrict__ blockPrefix,
                             int* __restrict__ offsets, int nb, int N) {
  int lane = threadIdx.x;  // 64 threads
  int carry = 0;
  for (int base = 0; base < nb; base += 64) {
    int i = base + lane;
    int v = (i < nb) ? blockSums[i] : 0;
    int inc = v;
#pragma unroll
    for (int d = 1; d < 64; d <<= 1) {
      int n = __shfl_up(inc, d);
      if (lane >= d) inc += n;
    }
    if (i < nb) blockPrefix[i] = carry + inc - v;
    carry += __shfl(inc, 63);
  }
  if (lane == 0) offsets[N] = carry;
}

__global__ void scanC_kernel(const int* __restrict__ blockPrefix, int* __restrict__ offsets,
                             int* __restrict__ cursor, int N) {
  int i = blockIdx.x * 256 + threadIdx.x;
  if (i < N) {
    int v = offsets[i] + blockPrefix[i >> 10];
    offsets[i] = v;
    cursor[i] = v;
  }
}

__global__ void scatter_kernel(const int* __restrict__ srcv, const int* __restrict__ dstv,
                               int* __restrict__ cursor, int* __restrict__ csr_src,
                               int E, int N) {
  int e = blockIdx.x * 256 + threadIdx.x;
  if (e < E) {
    int pos = atomicAdd(&cursor[dstv[e]], 1);
    csr_src[pos] = srcv[e];
  } else if (e < E + N) {
    int i = e - E;
    int pos = atomicAdd(&cursor[i], 1);
    csr_src[pos] = i;  // self loop
  }
}

// gemm1: xl = x@Wl + bl, xr = x@Wr + br.  x:[N,128], W:[128,128].
__global__ __launch_bounds__(256) void gemm1_kernel(const float* __restrict__ x,
    const float* __restrict__ Wl, const float* __restrict__ bl,
    const float* __restrict__ Wr, const float* __restrict__ br,
    float* __restrict__ xl, float* __restrict__ xr, int N) {
  __shared__ float xs[32 * 128];
  int t = threadIdx.x;
  int row0 = blockIdx.x * 32;
  const float4* xg4 = (const float4*)x;
  float4* xs4 = (float4*)xs;
  int b4 = row0 * 32;
  int lim4 = N * 32;
#pragma unroll
  for (int i = 0; i < 4; i++) {
    int idx = t + 256 * i;
    float4 v = make_float4(0.f, 0.f, 0.f, 0.f);
    if (b4 + idx < lim4) v = xg4[b4 + idx];
    xs4[idx] = v;
  }
  __syncthreads();
  int wv = t >> 6, l = t & 63;
  const float* W  = (l < 32) ? Wl : Wr;
  const float* bb = (l < 32) ? bl : br;
  float* outp     = (l < 32) ? xl : xr;
  int c = (l & 31) * 4;
  int rbase = wv * 8;
  float acc[8][4];
#pragma unroll
  for (int r = 0; r < 8; r++)
#pragma unroll
    for (int j = 0; j < 4; j++) acc[r][j] = 0.f;

  for (int k = 0; k < 128; k += 4) {
    float4 w0 = *(const float4*)(W + (k + 0) * 128 + c);
    float4 w1 = *(const float4*)(W + (k + 1) * 128 + c);
    float4 w2 = *(const float4*)(W + (k + 2) * 128 + c);
    float4 w3 = *(const float4*)(W + (k + 3) * 128 + c);
#pragma unroll
    for (int r = 0; r < 8; r++) {
      float4 xv = *(const float4*)(&xs[(rbase + r) * 128 + k]);
      acc[r][0] = fmaf(xv.x, w0.x, fmaf(xv.y, w1.x, fmaf(xv.z, w2.x, fmaf(xv.w, w3.x, acc[r][0]))));
      acc[r][1] = fmaf(xv.x, w0.y, fmaf(xv.y, w1.y, fmaf(xv.z, w2.y, fmaf(xv.w, w3.y, acc[r][1]))));
      acc[r][2] = fmaf(xv.x, w0.z, fmaf(xv.y, w1.z, fmaf(xv.z, w2.z, fmaf(xv.w, w3.z, acc[r][2]))));
      acc[r][3] = fmaf(xv.x, w0.w, fmaf(xv.y, w1.w, fmaf(xv.z, w2.w, fmaf(xv.w, w3.w, acc[r][3]))));
    }
  }
  float4 bv = *(const float4*)(bb + c);
#pragma unroll
  for (int r = 0; r < 8; r++) {
    int row = row0 + rbase + r;
    if (row < N) {
      float4 o = make_float4(acc[r][0] + bv.x, acc[r][1] + bv.y, acc[r][2] + bv.z, acc[r][3] + bv.w);
      *(float4*)(outp + (size_t)row * 128 + c) = o;
    }
  }
}

// gemm2: xl2 = h@Wl2 + bl2, xr2 = h@Wr2 + br2.  h:[N,128], W:[128,64].
__global__ __launch_bounds__(256) void gemm2_kernel(const float* __restrict__ h,
    const float* __restrict__ Wl, const float* __restrict__ bl,
    const float* __restrict__ Wr, const float* __restrict__ br,
    float* __restrict__ xl, float* __restrict__ xr, int N) {
  __shared__ float xs[64 * 128];
  int t = threadIdx.x;
  int row0 = blockIdx.x * 64;
  const float4* hg4 = (const float4*)h;
  float4* xs4 = (float4*)xs;
  int b4 = row0 * 32;
  int lim4 = N * 32;
#pragma unroll
  for (int i = 0; i < 8; i++) {
    int idx = t + 256 * i;
    float4 v = make_float4(0.f, 0.f, 0.f, 0.f);
    if (b4 + idx < lim4) v = hg4[b4 + idx];
    xs4[idx] = v;
  }
  __syncthreads();
  int wv = t >> 6, l = t & 63;
  int half = l >> 5, ll = l & 31;
  const float* W  = (ll < 16) ? Wl : Wr;
  const float* bb = (ll < 16) ? bl : br;
  float* outp     = (ll < 16) ? xl : xr;
  int c = (ll & 15) * 4;
  int rbase = wv * 16 + half * 8;
  float acc[8][4];
#pragma unroll
  for (int r = 0; r < 8; r++)
#pragma unroll
    for (int j = 0; j < 4; j++) acc[r][j] = 0.f;

  for (int k = 0; k < 128; k += 4) {
    float4 w0 = *(const float4*)(W + (k + 0) * 64 + c);
    float4 w1 = *(const float4*)(W + (k + 1) * 64 + c);
    float4 w2 = *(const float4*)(W + (k + 2) * 64 + c);
    float4 w3 = *(const float4*)(W + (k + 3) * 64 + c);
#pragma unroll
    for (int r = 0; r < 8; r++) {
      float4 xv = *(const float4*)(&xs[(rbase + r) * 128 + k]);
      acc[r][0] = fmaf(xv.x, w0.x, fmaf(xv.y, w1.x, fmaf(xv.z, w2.x, fmaf(xv.w, w3.x, acc[r][0]))));
      acc[r][1] = fmaf(xv.x, w0.y, fmaf(xv.y, w1.y, fmaf(xv.z, w2.y, fmaf(xv.w, w3.y, acc[r][1]))));
      acc[r][2] = fmaf(xv.x, w0.z, fmaf(xv.y, w1.z, fmaf(xv.z, w2.z, fmaf(xv.w, w3.z, acc[r][2]))));
      acc[r][3] = fmaf(xv.x, w0.w, fmaf(xv.y, w1.w, fmaf(xv.z, w2.w, fmaf(xv.w, w3.w, acc[r][3]))));
    }
  }
  float4 bv = *(const float4*)(bb + c);
#pragma unroll
  for (int r = 0; r < 8; r++) {
    int row = row0 + rbase + r;
    if (row < N) {
      float4 o = make_float4(acc[r][0] + bv.x, acc[r][1] + bv.y, acc[r][2] + bv.z, acc[r][3] + bv.w);
      *(float4*)(outp + (size_t)row * 64 + c) = o;
    }
  }
}

// edge1: one wave per dst node. 128 channels -> 2/lane. head = lane>>4 (16-lane groups).
// Unrolled x4: independent gathers + score reductions, single batched online-softmax update.
__global__ __launch_bounds__(256) void edge1_kernel(
    const float* __restrict__ xl, const float* __restrict__ xr,
    const float* __restrict__ att, const float* __restrict__ bias,
    const int* __restrict__ offsets, const int* __restrict__ csr_src,
    float* __restrict__ h, int N) {
  int node = blockIdx.x * 4 + (threadIdx.x >> 6);
  if (node >= N) return;
  int lane = threadIdx.x & 63;
  int c = lane * 2;
  float2 xri = *(const float2*)(xr + (size_t)node * 128 + c);
  float2 at  = *(const float2*)(att + c);
  int s0 = __builtin_amdgcn_readfirstlane(offsets[node]);
  int s1 = __builtin_amdgcn_readfirstlane(offsets[node + 1]);
  float m = -1e30f, l = 0.f, a0 = 0.f, a1 = 0.f;
  int e = s0;
  for (; e + 4 <= s1; e += 4) {
    int j0 = __builtin_amdgcn_readfirstlane(csr_src[e + 0]);
    int j1 = __builtin_amdgcn_readfirstlane(csr_src[e + 1]);
    int j2 = __builtin_amdgcn_readfirstlane(csr_src[e + 2]);
    int j3 = __builtin_amdgcn_readfirstlane(csr_src[e + 3]);
    float2 m0 = *(const float2*)(xl + (size_t)j0 * 128 + c);
    float2 m1 = *(const float2*)(xl + (size_t)j1 * 128 + c);
    float2 m2 = *(const float2*)(xl + (size_t)j2 * 128 + c);
    float2 m3 = *(const float2*)(xl + (size_t)j3 * 128 + c);
    float q0, q1, q2, q3;
    {
      float e0 = m0.x + xri.x; e0 = fmaxf(e0, NSLOPE * e0);
      float e1 = m0.y + xri.y; e1 = fmaxf(e1, NSLOPE * e1);
      q0 = fmaf(e0, at.x, e1 * at.y);
    }
    {
      float e0 = m1.x + xri.x; e0 = fmaxf(e0, NSLOPE * e0);
      float e1 = m1.y + xri.y; e1 = fmaxf(e1, NSLOPE * e1);
      q1 = fmaf(e0, at.x, e1 * at.y);
    }
    {
      float e0 = m2.x + xri.x; e0 = fmaxf(e0, NSLOPE * e0);
      float e1 = m2.y + xri.y; e1 = fmaxf(e1, NSLOPE * e1);
      q2 = fmaf(e0, at.x, e1 * at.y);
    }
    {
      float e0 = m3.x + xri.x; e0 = fmaxf(e0, NSLOPE * e0);
      float e1 = m3.y + xri.y; e1 = fmaxf(e1, NSLOPE * e1);
      q3 = fmaf(e0, at.x, e1 * at.y);
    }
    // 4 independent 16-lane reduces (chains interleave)
#pragma unroll
    for (int d = 1; d < 16; d <<= 1) {
      q0 += __shfl_xor(q0, d, 16);
      q1 += __shfl_xor(q1, d, 16);
      q2 += __shfl_xor(q2, d, 16);
      q3 += __shfl_xor(q3, d, 16);
    }
    float nm = fmaxf(m, fmaxf(fmaxf(q0, q1), fmaxf(q2, q3)));
    float scale = __expf(m - nm);
    float p0 = __expf(q0 - nm);
    float p1 = __expf(q1 - nm);
    float p2 = __expf(q2 - nm);
    float p3 = __expf(q3 - nm);
    l  = fmaf(l, scale, (p0 + p1) + (p2 + p3));
    a0 = fmaf(a0, scale, fmaf(p0, m0.x, fmaf(p1, m1.x, fmaf(p2, m2.x, p3 * m3.x))));
    a1 = fmaf(a1, scale, fmaf(p0, m0.y, fmaf(p1, m1.y, fmaf(p2, m2.y, p3 * m3.y))));
    m = nm;
  }
  for (; e < s1; e++) {
    int j = __builtin_amdgcn_readfirstlane(csr_src[e]);
    float2 msg = *(const float2*)(xl + (size_t)j * 128 + c);
    float e0 = msg.x + xri.x; e0 = fmaxf(e0, NSLOPE * e0);
    float e1 = msg.y + xri.y; e1 = fmaxf(e1, NSLOPE * e1);
    float p = fmaf(e0, at.x, e1 * at.y);
#pragma unroll
    for (int d = 1; d < 16; d <<= 1) p += __shfl_xor(p, d, 16);
    float nm = fmaxf(m, p);
    float scale = __expf(m - nm);
    float pe = __expf(p - nm);
    l  = fmaf(l, scale, pe);
    a0 = fmaf(a0, scale, pe * msg.x);
    a1 = fmaf(a1, scale, pe * msg.y);
    m = nm;
  }
  float inv = 1.f / l;
  float2 bb = *(const float2*)(bias + c);
  float o0 = fmaxf(fmaf(a0, inv, bb.x), 0.f);
  float o1 = fmaxf(fmaf(a1, inv, bb.y), 0.f);
  *(float2*)(h + (size_t)node * 128 + c) = make_float2(o0, o1);
}

// edge2: one wave per dst node. 64 channels -> 1/lane, 1 head (full-wave reduce). Unrolled x4.
__global__ __launch_bounds__(256) void edge2_kernel(
    const float* __restrict__ xl, const float* __restrict__ xr,
    const float* __restrict__ att, const float* __restrict__ bias,
    const int* __restrict__ offsets, const int* __restrict__ csr_src,
    float* __restrict__ out, int N) {
  int node = blockIdx.x * 4 + (threadIdx.x >> 6);
  if (node >= N) return;
  int lane = threadIdx.x & 63;
  float xri = xr[(size_t)node * 64 + lane];
  float at  = att[lane];
  int s0 = __builtin_amdgcn_readfirstlane(offsets[node]);
  int s1 = __builtin_amdgcn_readfirstlane(offsets[node + 1]);
  float m = -1e30f, l = 0.f, a = 0.f;
  int e = s0;
  for (; e + 4 <= s1; e += 4) {
    int j0 = __builtin_amdgcn_readfirstlane(csr_src[e + 0]);
    int j1 = __builtin_amdgcn_readfirstlane(csr_src[e + 1]);
    int j2 = __builtin_amdgcn_readfirstlane(csr_src[e + 2]);
    int j3 = __builtin_amdgcn_readfirstlane(csr_src[e + 3]);
    float m0 = xl[(size_t)j0 * 64 + lane];
    float m1 = xl[(size_t)j1 * 64 + lane];
    float m2 = xl[(size_t)j2 * 64 + lane];
    float m3 = xl[(size_t)j3 * 64 + lane];
    float q0 = m0 + xri; q0 = fmaxf(q0, NSLOPE * q0); q0 *= at;
    float q1 = m1 + xri; q1 = fmaxf(q1, NSLOPE * q1); q1 *= at;
    float q2 = m2 + xri; q2 = fmaxf(q2, NSLOPE * q2); q2 *= at;
    float q3 = m3 + xri; q3 = fmaxf(q3, NSLOPE * q3); q3 *= at;
#pragma unroll
    for (int d = 1; d < 64; d <<= 1) {
      q0 += __shfl_xor(q0, d);
      q1 += __shfl_xor(q1, d);
      q2 += __shfl_xor(q2, d);
      q3 += __shfl_xor(q3, d);
    }
    float nm = fmaxf(m, fmaxf(fmaxf(q0, q1), fmaxf(q2, q3)));
    float scale = __expf(m - nm);
    float p0 = __expf(q0 - nm);
    float p1 = __expf(q1 - nm);
    float p2 = __expf(q2 - nm);
    float p3 = __expf(q3 - nm);
    l = fmaf(l, scale, (p0 + p1) + (p2 + p3));
    a = fmaf(a, scale, fmaf(p0, m0, fmaf(p1, m1, fmaf(p2, m2, p3 * m3))));
    m = nm;
  }
  for (; e < s1; e++) {
    int j = __builtin_amdgcn_readfirstlane(csr_src[e]);
    float msg = xl[(size_t)j * 64 + lane];
    float ee = msg + xri; ee = fmaxf(ee, NSLOPE * ee);
    float p = ee * at;
#pragma unroll
    for (int d = 1; d < 64; d <<= 1) p += __shfl_xor(p, d);
    float nm = fmaxf(m, p);
    float scale = __expf(m - nm);
    float pe = __expf(p - nm);
    l = fmaf(l, scale, pe);
    a = fmaf(a, scale, pe * msg);
    m = nm;
  }
  out[(size_t)node * 64 + lane] = fmaf(a, 1.f / l, bias[lane]);
}

extern "C" void kernel_launch(void* const* d_in, const int* in_sizes, int n_in,
                              void* d_out, int out_size, void* d_ws, size_t ws_size,
                              hipStream_t stream) {
  const float* x    = (const float*)d_in[0];
  const int*   ei   = (const int*)d_in[1];
  const float* Wl1  = (const float*)d_in[2];
  const float* bl1  = (const float*)d_in[3];
  const float* Wr1  = (const float*)d_in[4];
  const float* br1  = (const float*)d_in[5];
  const float* att1 = (const float*)d_in[6];
  const float* bias1= (const float*)d_in[7];
  const float* Wl2  = (const float*)d_in[8];
  const float* bl2  = (const float*)d_in[9];
  const float* Wr2  = (const float*)d_in[10];
  const float* br2  = (const float*)d_in[11];
  const float* att2 = (const float*)d_in[12];
  const float* bias2= (const float*)d_in[13];
  float* out = (float*)d_out;

  const int N = in_sizes[0] / 128;
  const int E = in_sizes[1] / 2;
  const int Etot = E + N;
  const int* srcv = ei;
  const int* dstv = ei + E;

  char* ws = (char*)d_ws;
  size_t off = 0;
  auto alloc = [&](size_t bytes) -> void* {
    void* p = ws + off;
    off = (off + bytes + 255) & ~(size_t)255;
    return p;
  };
  int* offsets     = (int*)alloc((size_t)(N + 1) * 4);
  int* cursor      = (int*)alloc((size_t)N * 4);
  int* counts      = (int*)alloc((size_t)N * 4);
  int* blockSums   = (int*)alloc(256 * 4);
  int* blockPrefix = (int*)alloc(256 * 4);
  int* csr_src     = (int*)alloc((size_t)Etot * 4);
  float* xl1 = (float*)alloc((size_t)N * 128 * 4);
  float* xr1 = (float*)alloc((size_t)N * 128 * 4);
  float* hbuf= (float*)alloc((size_t)N * 128 * 4);
  float* xl2 = xl1;  // reuse (xl1/xr1 dead after edge1)
  float* xr2 = xr1;
  (void)ws_size; (void)n_in; (void)out_size;

  int nb = (N + 1023) / 1024;

  zero_counts_kernel<<<(N + 255) / 256, 256, 0, stream>>>(counts, N);
  count_kernel<<<(E + 255) / 256, 256, 0, stream>>>(dstv, counts, E);
  scanA_kernel<<<nb, 256, 0, stream>>>(counts, offsets, blockSums, N);
  scanB_kernel<<<1, 64, 0, stream>>>(blockSums, blockPrefix, offsets, nb, N);
  scanC_kernel<<<(N + 255) / 256, 256, 0, stream>>>(blockPrefix, offsets, cursor, N);
  scatter_kernel<<<(Etot + 255) / 256, 256, 0, stream>>>(srcv, dstv, cursor, csr_src, E, N);
  gemm1_kernel<<<(N + 31) / 32, 256, 0, stream>>>(x, Wl1, bl1, Wr1, br1, xl1, xr1, N);
  edge1_kernel<<<(N + 3) / 4, 256, 0, stream>>>(xl1, xr1, att1, bias1, offsets, csr_src, hbuf, N);
  gemm2_kernel<<<(N + 63) / 64, 256, 0, stream>>>(hbuf, Wl2, bl2, Wr2, br2, xl2, xr2, N);
  edge2_kernel<<<(N + 3) / 4, 256, 0, stream>>>(xl2, xr2, att2, bias2, offsets, csr_src, out, N);
}

// Round 3
// 372.433 us; speedup vs baseline: 1.1874x; 1.0574x over previous
//
#include <hip/hip_runtime.h>
#include <hip/hip_bf16.h>
#include <math.h>

// GATv2 x2 layers. N=50000, E=800000 (+N self loops), D_in=128, H=4, Hd=32 (HC=128), D_out=64.
// R1: edge kernels unrolled x4 (batched online softmax).
// R2: GEMMs -> bf16x3 split MFMA (hi*hi + hi*lo + lo*hi), W pre-swizzled to fragment layout.

#define NSLOPE 0.2f

typedef __attribute__((ext_vector_type(8))) short short8;
typedef __attribute__((ext_vector_type(4))) float f32x4;

__device__ inline unsigned short f2bf(float f) {
  unsigned int u = __float_as_uint(f);
  u += 0x7fff + ((u >> 16) & 1);   // round-to-nearest-even
  return (unsigned short)(u >> 16);
}
__device__ inline float bf2f(unsigned short h) {
  return __uint_as_float(((unsigned int)h) << 16);
}

// ---------------- CSR build ----------------

__global__ void zero_counts_kernel(int* __restrict__ counts, int n) {
  int i = blockIdx.x * 256 + threadIdx.x;
  if (i < n) counts[i] = 0;
}

__global__ void count_kernel(const int* __restrict__ dst, int* __restrict__ counts, int E) {
  int e = blockIdx.x * 256 + threadIdx.x;
  if (e < E) atomicAdd(&counts[dst[e]], 1);
}

__global__ __launch_bounds__(256) void scanA_kernel(const int* __restrict__ counts,
                                                    int* __restrict__ offsets,
                                                    int* __restrict__ blockSums, int N) {
  int t = threadIdx.x;
  int lane = t & 63, wv = t >> 6;
  int g0 = blockIdx.x * 1024 + t * 4;
  int v[4];
#pragma unroll
  for (int u = 0; u < 4; u++) {
    int i = g0 + u;
    v[u] = (i < N) ? (counts[i] + 1) : 0;
  }
  int s = v[0] + v[1] + v[2] + v[3];
  int inc = s;
#pragma unroll
  for (int d = 1; d < 64; d <<= 1) {
    int n = __shfl_up(inc, d);
    if (lane >= d) inc += n;
  }
  __shared__ int wsum[4];
  if (lane == 63) wsum[wv] = inc;
  __syncthreads();
  int wprefix = 0;
#pragma unroll
  for (int w = 0; w < 4; w++)
    if (w < wv) wprefix += wsum[w];
  int run = wprefix + inc - s;
#pragma unroll
  for (int u = 0; u < 4; u++) {
    int i = g0 + u;
    if (i < N) offsets[i] = run;
    run += v[u];
  }
  if (t == 255) blockSums[blockIdx.x] = wprefix + inc;
}

__global__ void scanB_kernel(const int* __restrict__ blockSums, int* __restrict__ blockPrefix,
                             int* __restrict__ offsets, int nb, int N) {
  int lane = threadIdx.x;  // 64 threads
  int carry = 0;
  for (int base = 0; base < nb; base += 64) {
    int i = base + lane;
    int v = (i < nb) ? blockSums[i] : 0;
    int inc = v;
#pragma unroll
    for (int d = 1; d < 64; d <<= 1) {
      int n = __shfl_up(inc, d);
      if (lane >= d) inc += n;
    }
    if (i < nb) blockPrefix[i] = carry + inc - v;
    carry += __shfl(inc, 63);
  }
  if (lane == 0) offsets[N] = carry;
}

__global__ void scanC_kernel(const int* __restrict__ blockPrefix, int* __restrict__ offsets,
                             int* __restrict__ cursor, int N) {
  int i = blockIdx.x * 256 + threadIdx.x;
  if (i < N) {
    int v = offsets[i] + blockPrefix[i >> 10];
    offsets[i] = v;
    cursor[i] = v;
  }
}

__global__ void scatter_kernel(const int* __restrict__ srcv, const int* __restrict__ dstv,
                               int* __restrict__ cursor, int* __restrict__ csr_src,
                               int E, int N) {
  int e = blockIdx.x * 256 + threadIdx.x;
  if (e < E) {
    int pos = atomicAdd(&cursor[dstv[e]], 1);
    csr_src[pos] = srcv[e];
  } else if (e < E + N) {
    int i = e - E;
    int pos = atomicAdd(&cursor[i], 1);
    csr_src[pos] = i;  // self loop
  }
}

// ---------------- MFMA GEMM (bf16x3 split) ----------------
// B fragment layout (per 16x16x32 tile): lane l holds B[k=kt*32+(l>>4)*8+j][n=tn*16+(l&15)],
// stored as [tn][kt][lane][j] contiguous shorts (16B per lane -> coalesced dwordx4).

__global__ __launch_bounds__(256) void prep_b_kernel(const float* __restrict__ Wl,
    const float* __restrict__ Wr, int C,
    unsigned short* __restrict__ Bhi, unsigned short* __restrict__ Blo, int total) {
  int t = blockIdx.x * 256 + threadIdx.x;
  if (t >= total) return;
  int lane = t & 63;
  int kt = (t >> 6) & 3;
  int tn = t >> 8;
  int n = tn * 16 + (lane & 15);
  int k0 = kt * 32 + ((lane >> 4) * 8);
  const float* W = (n < C) ? (Wl + n) : (Wr + (n - C));
  size_t base = ((size_t)(tn * 4 + kt) * 64 + lane) * 8;
#pragma unroll
  for (int j = 0; j < 8; j++) {
    float v = W[(size_t)(k0 + j) * C];
    unsigned short hi = f2bf(v);
    Bhi[base + j] = hi;
    Blo[base + j] = f2bf(v - bf2f(hi));
  }
}

// A:[M,128] f32. Block: 128 rows x 64 cols (col-group g = blockIdx.y).
// Wave: 32 rows (2 m-tiles) x 4 n-tiles. K=128 (4 k-steps of 32).
// out split: n<C -> xl[:,n], else xr[:,n-C]; bias bl/br added.
__global__ __launch_bounds__(256) void gemm_mfma_kernel(const float* __restrict__ A,
    const unsigned short* __restrict__ Bhi, const unsigned short* __restrict__ Blo,
    const float* __restrict__ bl, const float* __restrict__ br,
    float* __restrict__ xl, float* __restrict__ xr, int C, int M) {
  __shared__ unsigned short sBh[16 * 512];  // 16KB: 4 n-tiles x 4 k-tiles x 64 lanes x 8
  __shared__ unsigned short sBl[16 * 512];
  int t = threadIdx.x;
  int g = blockIdx.y;
  {
    const float4* srcH = (const float4*)(Bhi + (size_t)g * 8192);
    const float4* srcL = (const float4*)(Blo + (size_t)g * 8192);
    float4* dH = (float4*)sBh;
    float4* dL = (float4*)sBl;
#pragma unroll
    for (int i = 0; i < 4; i++) {
      dH[t + 256 * i] = srcH[t + 256 * i];
      dL[t + 256 * i] = srcL[t + 256 * i];
    }
  }
  __syncthreads();
  int w = t >> 6, l = t & 63;
  int m_base = blockIdx.x * 128 + w * 32;
  int mrow = l & 15;
  int kq = l >> 4;
  f32x4 acc[2][4];
#pragma unroll
  for (int mt = 0; mt < 2; mt++)
#pragma unroll
    for (int tn = 0; tn < 4; tn++) acc[mt][tn] = (f32x4){0.f, 0.f, 0.f, 0.f};

#pragma unroll
  for (int kt = 0; kt < 4; kt++) {
    short8 ah[2], al[2];
#pragma unroll
    for (int mt = 0; mt < 2; mt++) {
      int m = m_base + mt * 16 + mrow;
      m = (m < M) ? m : (M - 1);
      const float* pa = A + (size_t)m * 128 + kt * 32 + kq * 8;
      float4 v0 = *(const float4*)pa;
      float4 v1 = *(const float4*)(pa + 4);
      float f[8] = {v0.x, v0.y, v0.z, v0.w, v1.x, v1.y, v1.z, v1.w};
#pragma unroll
      for (int j = 0; j < 8; j++) {
        unsigned short hi = f2bf(f[j]);
        ah[mt][j] = (short)hi;
        al[mt][j] = (short)f2bf(f[j] - bf2f(hi));
      }
    }
#pragma unroll
    for (int tn = 0; tn < 4; tn++) {
      int off = ((tn * 4 + kt) * 64 + l) * 8;
      short8 bh = *(const short8*)(sBh + off);
      short8 blo = *(const short8*)(sBl + off);
#pragma unroll
      for (int mt = 0; mt < 2; mt++) {
        acc[mt][tn] = __builtin_amdgcn_mfma_f32_16x16x32_bf16(ah[mt], bh, acc[mt][tn], 0, 0, 0);
        acc[mt][tn] = __builtin_amdgcn_mfma_f32_16x16x32_bf16(ah[mt], blo, acc[mt][tn], 0, 0, 0);
        acc[mt][tn] = __builtin_amdgcn_mfma_f32_16x16x32_bf16(al[mt], bh, acc[mt][tn], 0, 0, 0);
      }
    }
  }
#pragma unroll
  for (int tn = 0; tn < 4; tn++) {
    int n = g * 64 + tn * 16 + mrow;
    float bias = (n < C) ? bl[n] : br[n - C];
    float* outp = (n < C) ? (xl + n) : (xr + (n - C));
#pragma unroll
    for (int mt = 0; mt < 2; mt++) {
#pragma unroll
      for (int r = 0; r < 4; r++) {
        int m = m_base + mt * 16 + kq * 4 + r;
        if (m < M) outp[(size_t)m * C] = acc[mt][tn][r] + bias;
      }
    }
  }
}

// ---------------- edge kernels (unchanged from R1) ----------------

__global__ __launch_bounds__(256) void edge1_kernel(
    const float* __restrict__ xl, const float* __restrict__ xr,
    const float* __restrict__ att, const float* __restrict__ bias,
    const int* __restrict__ offsets, const int* __restrict__ csr_src,
    float* __restrict__ h, int N) {
  int node = blockIdx.x * 4 + (threadIdx.x >> 6);
  if (node >= N) return;
  int lane = threadIdx.x & 63;
  int c = lane * 2;
  float2 xri = *(const float2*)(xr + (size_t)node * 128 + c);
  float2 at  = *(const float2*)(att + c);
  int s0 = __builtin_amdgcn_readfirstlane(offsets[node]);
  int s1 = __builtin_amdgcn_readfirstlane(offsets[node + 1]);
  float m = -1e30f, l = 0.f, a0 = 0.f, a1 = 0.f;
  int e = s0;
  for (; e + 4 <= s1; e += 4) {
    int j0 = __builtin_amdgcn_readfirstlane(csr_src[e + 0]);
    int j1 = __builtin_amdgcn_readfirstlane(csr_src[e + 1]);
    int j2 = __builtin_amdgcn_readfirstlane(csr_src[e + 2]);
    int j3 = __builtin_amdgcn_readfirstlane(csr_src[e + 3]);
    float2 m0 = *(const float2*)(xl + (size_t)j0 * 128 + c);
    float2 m1 = *(const float2*)(xl + (size_t)j1 * 128 + c);
    float2 m2 = *(const float2*)(xl + (size_t)j2 * 128 + c);
    float2 m3 = *(const float2*)(xl + (size_t)j3 * 128 + c);
    float q0, q1, q2, q3;
    {
      float e0 = m0.x + xri.x; e0 = fmaxf(e0, NSLOPE * e0);
      float e1 = m0.y + xri.y; e1 = fmaxf(e1, NSLOPE * e1);
      q0 = fmaf(e0, at.x, e1 * at.y);
    }
    {
      float e0 = m1.x + xri.x; e0 = fmaxf(e0, NSLOPE * e0);
      float e1 = m1.y + xri.y; e1 = fmaxf(e1, NSLOPE * e1);
      q1 = fmaf(e0, at.x, e1 * at.y);
    }
    {
      float e0 = m2.x + xri.x; e0 = fmaxf(e0, NSLOPE * e0);
      float e1 = m2.y + xri.y; e1 = fmaxf(e1, NSLOPE * e1);
      q2 = fmaf(e0, at.x, e1 * at.y);
    }
    {
      float e0 = m3.x + xri.x; e0 = fmaxf(e0, NSLOPE * e0);
      float e1 = m3.y + xri.y; e1 = fmaxf(e1, NSLOPE * e1);
      q3 = fmaf(e0, at.x, e1 * at.y);
    }
#pragma unroll
    for (int d = 1; d < 16; d <<= 1) {
      q0 += __shfl_xor(q0, d, 16);
      q1 += __shfl_xor(q1, d, 16);
      q2 += __shfl_xor(q2, d, 16);
      q3 += __shfl_xor(q3, d, 16);
    }
    float nm = fmaxf(m, fmaxf(fmaxf(q0, q1), fmaxf(q2, q3)));
    float scale = __expf(m - nm);
    float p0 = __expf(q0 - nm);
    float p1 = __expf(q1 - nm);
    float p2 = __expf(q2 - nm);
    float p3 = __expf(q3 - nm);
    l  = fmaf(l, scale, (p0 + p1) + (p2 + p3));
    a0 = fmaf(a0, scale, fmaf(p0, m0.x, fmaf(p1, m1.x, fmaf(p2, m2.x, p3 * m3.x))));
    a1 = fmaf(a1, scale, fmaf(p0, m0.y, fmaf(p1, m1.y, fmaf(p2, m2.y, p3 * m3.y))));
    m = nm;
  }
  for (; e < s1; e++) {
    int j = __builtin_amdgcn_readfirstlane(csr_src[e]);
    float2 msg = *(const float2*)(xl + (size_t)j * 128 + c);
    float e0 = msg.x + xri.x; e0 = fmaxf(e0, NSLOPE * e0);
    float e1 = msg.y + xri.y; e1 = fmaxf(e1, NSLOPE * e1);
    float p = fmaf(e0, at.x, e1 * at.y);
#pragma unroll
    for (int d = 1; d < 16; d <<= 1) p += __shfl_xor(p, d, 16);
    float nm = fmaxf(m, p);
    float scale = __expf(m - nm);
    float pe = __expf(p - nm);
    l  = fmaf(l, scale, pe);
    a0 = fmaf(a0, scale, pe * msg.x);
    a1 = fmaf(a1, scale, pe * msg.y);
    m = nm;
  }
  float inv = 1.f / l;
  float2 bb = *(const float2*)(bias + c);
  float o0 = fmaxf(fmaf(a0, inv, bb.x), 0.f);
  float o1 = fmaxf(fmaf(a1, inv, bb.y), 0.f);
  *(float2*)(h + (size_t)node * 128 + c) = make_float2(o0, o1);
}

__global__ __launch_bounds__(256) void edge2_kernel(
    const float* __restrict__ xl, const float* __restrict__ xr,
    const float* __restrict__ att, const float* __restrict__ bias,
    const int* __restrict__ offsets, const int* __restrict__ csr_src,
    float* __restrict__ out, int N) {
  int node = blockIdx.x * 4 + (threadIdx.x >> 6);
  if (node >= N) return;
  int lane = threadIdx.x & 63;
  float xri = xr[(size_t)node * 64 + lane];
  float at  = att[lane];
  int s0 = __builtin_amdgcn_readfirstlane(offsets[node]);
  int s1 = __builtin_amdgcn_readfirstlane(offsets[node + 1]);
  float m = -1e30f, l = 0.f, a = 0.f;
  int e = s0;
  for (; e + 4 <= s1; e += 4) {
    int j0 = __builtin_amdgcn_readfirstlane(csr_src[e + 0]);
    int j1 = __builtin_amdgcn_readfirstlane(csr_src[e + 1]);
    int j2 = __builtin_amdgcn_readfirstlane(csr_src[e + 2]);
    int j3 = __builtin_amdgcn_readfirstlane(csr_src[e + 3]);
    float m0 = xl[(size_t)j0 * 64 + lane];
    float m1 = xl[(size_t)j1 * 64 + lane];
    float m2 = xl[(size_t)j2 * 64 + lane];
    float m3 = xl[(size_t)j3 * 64 + lane];
    float q0 = m0 + xri; q0 = fmaxf(q0, NSLOPE * q0); q0 *= at;
    float q1 = m1 + xri; q1 = fmaxf(q1, NSLOPE * q1); q1 *= at;
    float q2 = m2 + xri; q2 = fmaxf(q2, NSLOPE * q2); q2 *= at;
    float q3 = m3 + xri; q3 = fmaxf(q3, NSLOPE * q3); q3 *= at;
#pragma unroll
    for (int d = 1; d < 64; d <<= 1) {
      q0 += __shfl_xor(q0, d);
      q1 += __shfl_xor(q1, d);
      q2 += __shfl_xor(q2, d);
      q3 += __shfl_xor(q3, d);
    }
    float nm = fmaxf(m, fmaxf(fmaxf(q0, q1), fmaxf(q2, q3)));
    float scale = __expf(m - nm);
    float p0 = __expf(q0 - nm);
    float p1 = __expf(q1 - nm);
    float p2 = __expf(q2 - nm);
    float p3 = __expf(q3 - nm);
    l = fmaf(l, scale, (p0 + p1) + (p2 + p3));
    a = fmaf(a, scale, fmaf(p0, m0, fmaf(p1, m1, fmaf(p2, m2, p3 * m3))));
    m = nm;
  }
  for (; e < s1; e++) {
    int j = __builtin_amdgcn_readfirstlane(csr_src[e]);
    float msg = xl[(size_t)j * 64 + lane];
    float ee = msg + xri; ee = fmaxf(ee, NSLOPE * ee);
    float p = ee * at;
#pragma unroll
    for (int d = 1; d < 64; d <<= 1) p += __shfl_xor(p, d);
    float nm = fmaxf(m, p);
    float scale = __expf(m - nm);
    float pe = __expf(p - nm);
    l = fmaf(l, scale, pe);
    a = fmaf(a, scale, pe * msg);
    m = nm;
  }
  out[(size_t)node * 64 + lane] = fmaf(a, 1.f / l, bias[lane]);
}

extern "C" void kernel_launch(void* const* d_in, const int* in_sizes, int n_in,
                              void* d_out, int out_size, void* d_ws, size_t ws_size,
                              hipStream_t stream) {
  const float* x    = (const float*)d_in[0];
  const int*   ei   = (const int*)d_in[1];
  const float* Wl1  = (const float*)d_in[2];
  const float* bl1  = (const float*)d_in[3];
  const float* Wr1  = (const float*)d_in[4];
  const float* br1  = (const float*)d_in[5];
  const float* att1 = (const float*)d_in[6];
  const float* bias1= (const float*)d_in[7];
  const float* Wl2  = (const float*)d_in[8];
  const float* bl2  = (const float*)d_in[9];
  const float* Wr2  = (const float*)d_in[10];
  const float* br2  = (const float*)d_in[11];
  const float* att2 = (const float*)d_in[12];
  const float* bias2= (const float*)d_in[13];
  float* out = (float*)d_out;

  const int N = in_sizes[0] / 128;
  const int E = in_sizes[1] / 2;
  const int Etot = E + N;
  const int* srcv = ei;
  const int* dstv = ei + E;

  char* ws = (char*)d_ws;
  size_t off = 0;
  auto alloc = [&](size_t bytes) -> void* {
    void* p = ws + off;
    off = (off + bytes + 255) & ~(size_t)255;
    return p;
  };
  int* offsets     = (int*)alloc((size_t)(N + 1) * 4);
  int* cursor      = (int*)alloc((size_t)N * 4);
  int* counts      = (int*)alloc((size_t)N * 4);
  int* blockSums   = (int*)alloc(256 * 4);
  int* blockPrefix = (int*)alloc(256 * 4);
  int* csr_src     = (int*)alloc((size_t)Etot * 4);
  unsigned short* B1hi = (unsigned short*)alloc(16 * 4 * 64 * 8 * 2);
  unsigned short* B1lo = (unsigned short*)alloc(16 * 4 * 64 * 8 * 2);
  unsigned short* B2hi = (unsigned short*)alloc(8 * 4 * 64 * 8 * 2);
  unsigned short* B2lo = (unsigned short*)alloc(8 * 4 * 64 * 8 * 2);
  float* xl1 = (float*)alloc((size_t)N * 128 * 4);
  float* xr1 = (float*)alloc((size_t)N * 128 * 4);
  float* hbuf= (float*)alloc((size_t)N * 128 * 4);
  float* xl2 = xl1;  // reuse (xl1/xr1 dead after edge1)
  float* xr2 = xr1;
  (void)ws_size; (void)n_in; (void)out_size;

  int nb = (N + 1023) / 1024;
  int mb = (N + 127) / 128;

  zero_counts_kernel<<<(N + 255) / 256, 256, 0, stream>>>(counts, N);
  count_kernel<<<(E + 255) / 256, 256, 0, stream>>>(dstv, counts, E);
  scanA_kernel<<<nb, 256, 0, stream>>>(counts, offsets, blockSums, N);
  scanB_kernel<<<1, 64, 0, stream>>>(blockSums, blockPrefix, offsets, nb, N);
  scanC_kernel<<<(N + 255) / 256, 256, 0, stream>>>(blockPrefix, offsets, cursor, N);
  scatter_kernel<<<(Etot + 255) / 256, 256, 0, stream>>>(srcv, dstv, cursor, csr_src, E, N);

  prep_b_kernel<<<16, 256, 0, stream>>>(Wl1, Wr1, 128, B1hi, B1lo, 16 * 4 * 64);
  prep_b_kernel<<<8, 256, 0, stream>>>(Wl2, Wr2, 64, B2hi, B2lo, 8 * 4 * 64);

  gemm_mfma_kernel<<<dim3(mb, 4), 256, 0, stream>>>(x, B1hi, B1lo, bl1, br1, xl1, xr1, 128, N);
  edge1_kernel<<<(N + 3) / 4, 256, 0, stream>>>(xl1, xr1, att1, bias1, offsets, csr_src, hbuf, N);
  gemm_mfma_kernel<<<dim3(mb, 2), 256, 0, stream>>>(hbuf, B2hi, B2lo, bl2, br2, xl2, xr2, 64, N);
  edge2_kernel<<<(N + 3) / 4, 256, 0, stream>>>(xl2, xr2, att2, bias2, offsets, csr_src, out, N);
}

// Round 4
// 358.729 us; speedup vs baseline: 1.2328x; 1.0382x over previous
//
#include <hip/hip_runtime.h>
#include <hip/hip_bf16.h>
#include <math.h>

// GATv2 x2 layers. N=50000, E=800000 (+N self loops), D_in=128, H=4, Hd=32 (HC=128), D_out=64.
// R1: edge kernels unrolled (batched online softmax).
// R2: GEMMs -> bf16x3 split MFMA, W pre-swizzled to fragment layout.
// R3: no-max-shift softmax (scores |s|<~1.5; shift-invariant) -> edge loop is a pure
//     reduction, unrolled x8. scatter/count x4 edges/thread (atomic ILP). Self-loop
//     slot computed deterministically in scanC (no atomic).

#define NSLOPE 0.2f

typedef __attribute__((ext_vector_type(8))) short short8;
typedef __attribute__((ext_vector_type(4))) float f32x4;

__device__ inline unsigned short f2bf(float f) {
  unsigned int u = __float_as_uint(f);
  u += 0x7fff + ((u >> 16) & 1);   // round-to-nearest-even
  return (unsigned short)(u >> 16);
}
__device__ inline float bf2f(unsigned short h) {
  return __uint_as_float(((unsigned int)h) << 16);
}

// ---------------- CSR build ----------------

__global__ void zero_counts_kernel(int* __restrict__ counts, int n) {
  int i = blockIdx.x * 256 + threadIdx.x;
  if (i < n) counts[i] = 0;
}

// 4 edges/thread: independent atomics for MLP.
__global__ void count_kernel(const int* __restrict__ dst, int* __restrict__ counts, int E) {
  int e = (blockIdx.x * 256 + threadIdx.x) * 4;
  if (e + 4 <= E) {
    int d0 = dst[e + 0], d1 = dst[e + 1], d2 = dst[e + 2], d3 = dst[e + 3];
    atomicAdd(&counts[d0], 1);
    atomicAdd(&counts[d1], 1);
    atomicAdd(&counts[d2], 1);
    atomicAdd(&counts[d3], 1);
  } else {
    for (; e < E; e++) atomicAdd(&counts[dst[e]], 1);
  }
}

__global__ __launch_bounds__(256) void scanA_kernel(const int* __restrict__ counts,
                                                    int* __restrict__ offsets,
                                                    int* __restrict__ blockSums, int N) {
  int t = threadIdx.x;
  int lane = t & 63, wv = t >> 6;
  int g0 = blockIdx.x * 1024 + t * 4;
  int v[4];
#pragma unroll
  for (int u = 0; u < 4; u++) {
    int i = g0 + u;
    v[u] = (i < N) ? (counts[i] + 1) : 0;
  }
  int s = v[0] + v[1] + v[2] + v[3];
  int inc = s;
#pragma unroll
  for (int d = 1; d < 64; d <<= 1) {
    int n = __shfl_up(inc, d);
    if (lane >= d) inc += n;
  }
  __shared__ int wsum[4];
  if (lane == 63) wsum[wv] = inc;
  __syncthreads();
  int wprefix = 0;
#pragma unroll
  for (int w = 0; w < 4; w++)
    if (w < wv) wprefix += wsum[w];
  int run = wprefix + inc - s;
#pragma unroll
  for (int u = 0; u < 4; u++) {
    int i = g0 + u;
    if (i < N) offsets[i] = run;
    run += v[u];
  }
  if (t == 255) blockSums[blockIdx.x] = wprefix + inc;
}

__global__ void scanB_kernel(const int* __restrict__ blockSums, int* __restrict__ blockPrefix,
                             int* __restrict__ offsets, int nb, int N) {
  int lane = threadIdx.x;  // 64 threads
  int carry = 0;
  for (int base = 0; base < nb; base += 64) {
    int i = base + lane;
    int v = (i < nb) ? blockSums[i] : 0;
    int inc = v;
#pragma unroll
    for (int d = 1; d < 64; d <<= 1) {
      int n = __shfl_up(inc, d);
      if (lane >= d) inc += n;
    }
    if (i < nb) blockPrefix[i] = carry + inc - v;
    carry += __shfl(inc, 63);
  }
  if (lane == 0) offsets[N] = carry;
}

// finalize offsets, init cursor, and drop the self-loop into its deterministic slot.
__global__ void scanC_kernel(const int* __restrict__ blockPrefix, const int* __restrict__ counts,
                             int* __restrict__ offsets, int* __restrict__ cursor,
                             int* __restrict__ csr_src, int N) {
  int i = blockIdx.x * 256 + threadIdx.x;
  if (i < N) {
    int v = offsets[i] + blockPrefix[i >> 10];
    offsets[i] = v;
    cursor[i] = v;
    csr_src[v + counts[i]] = i;  // self loop occupies the segment's last slot
  }
}

// 4 edges/thread: 4 independent atomic->store chains.
__global__ void scatter_kernel(const int* __restrict__ srcv, const int* __restrict__ dstv,
                               int* __restrict__ cursor, int* __restrict__ csr_src, int E) {
  int e = (blockIdx.x * 256 + threadIdx.x) * 4;
  if (e + 4 <= E) {
    int d0 = dstv[e + 0], d1 = dstv[e + 1], d2 = dstv[e + 2], d3 = dstv[e + 3];
    int s0 = srcv[e + 0], s1 = srcv[e + 1], s2 = srcv[e + 2], s3 = srcv[e + 3];
    int p0 = atomicAdd(&cursor[d0], 1);
    int p1 = atomicAdd(&cursor[d1], 1);
    int p2 = atomicAdd(&cursor[d2], 1);
    int p3 = atomicAdd(&cursor[d3], 1);
    csr_src[p0] = s0;
    csr_src[p1] = s1;
    csr_src[p2] = s2;
    csr_src[p3] = s3;
  } else {
    for (; e < E; e++) {
      int pos = atomicAdd(&cursor[dstv[e]], 1);
      csr_src[pos] = srcv[e];
    }
  }
}

// ---------------- MFMA GEMM (bf16x3 split) ----------------

__global__ __launch_bounds__(256) void prep_b_kernel(const float* __restrict__ Wl,
    const float* __restrict__ Wr, int C,
    unsigned short* __restrict__ Bhi, unsigned short* __restrict__ Blo, int total) {
  int t = blockIdx.x * 256 + threadIdx.x;
  if (t >= total) return;
  int lane = t & 63;
  int kt = (t >> 6) & 3;
  int tn = t >> 8;
  int n = tn * 16 + (lane & 15);
  int k0 = kt * 32 + ((lane >> 4) * 8);
  const float* W = (n < C) ? (Wl + n) : (Wr + (n - C));
  size_t base = ((size_t)(tn * 4 + kt) * 64 + lane) * 8;
#pragma unroll
  for (int j = 0; j < 8; j++) {
    float v = W[(size_t)(k0 + j) * C];
    unsigned short hi = f2bf(v);
    Bhi[base + j] = hi;
    Blo[base + j] = f2bf(v - bf2f(hi));
  }
}

__global__ __launch_bounds__(256) void gemm_mfma_kernel(const float* __restrict__ A,
    const unsigned short* __restrict__ Bhi, const unsigned short* __restrict__ Blo,
    const float* __restrict__ bl, const float* __restrict__ br,
    float* __restrict__ xl, float* __restrict__ xr, int C, int M) {
  __shared__ unsigned short sBh[16 * 512];
  __shared__ unsigned short sBl[16 * 512];
  int t = threadIdx.x;
  int g = blockIdx.y;
  {
    const float4* srcH = (const float4*)(Bhi + (size_t)g * 8192);
    const float4* srcL = (const float4*)(Blo + (size_t)g * 8192);
    float4* dH = (float4*)sBh;
    float4* dL = (float4*)sBl;
#pragma unroll
    for (int i = 0; i < 4; i++) {
      dH[t + 256 * i] = srcH[t + 256 * i];
      dL[t + 256 * i] = srcL[t + 256 * i];
    }
  }
  __syncthreads();
  int w = t >> 6, l = t & 63;
  int m_base = blockIdx.x * 128 + w * 32;
  int mrow = l & 15;
  int kq = l >> 4;
  f32x4 acc[2][4];
#pragma unroll
  for (int mt = 0; mt < 2; mt++)
#pragma unroll
    for (int tn = 0; tn < 4; tn++) acc[mt][tn] = (f32x4){0.f, 0.f, 0.f, 0.f};

#pragma unroll
  for (int kt = 0; kt < 4; kt++) {
    short8 ah[2], al[2];
#pragma unroll
    for (int mt = 0; mt < 2; mt++) {
      int m = m_base + mt * 16 + mrow;
      m = (m < M) ? m : (M - 1);
      const float* pa = A + (size_t)m * 128 + kt * 32 + kq * 8;
      float4 v0 = *(const float4*)pa;
      float4 v1 = *(const float4*)(pa + 4);
      float f[8] = {v0.x, v0.y, v0.z, v0.w, v1.x, v1.y, v1.z, v1.w};
#pragma unroll
      for (int j = 0; j < 8; j++) {
        unsigned short hi = f2bf(f[j]);
        ah[mt][j] = (short)hi;
        al[mt][j] = (short)f2bf(f[j] - bf2f(hi));
      }
    }
#pragma unroll
    for (int tn = 0; tn < 4; tn++) {
      int off = ((tn * 4 + kt) * 64 + l) * 8;
      short8 bh = *(const short8*)(sBh + off);
      short8 blo = *(const short8*)(sBl + off);
#pragma unroll
      for (int mt = 0; mt < 2; mt++) {
        acc[mt][tn] = __builtin_amdgcn_mfma_f32_16x16x32_bf16(ah[mt], bh, acc[mt][tn], 0, 0, 0);
        acc[mt][tn] = __builtin_amdgcn_mfma_f32_16x16x32_bf16(ah[mt], blo, acc[mt][tn], 0, 0, 0);
        acc[mt][tn] = __builtin_amdgcn_mfma_f32_16x16x32_bf16(al[mt], bh, acc[mt][tn], 0, 0, 0);
      }
    }
  }
#pragma unroll
  for (int tn = 0; tn < 4; tn++) {
    int n = g * 64 + tn * 16 + mrow;
    float bias = (n < C) ? bl[n] : br[n - C];
    float* outp = (n < C) ? (xl + n) : (xr + (n - C));
#pragma unroll
    for (int mt = 0; mt < 2; mt++) {
#pragma unroll
      for (int r = 0; r < 4; r++) {
        int m = m_base + mt * 16 + kq * 4 + r;
        if (m < M) outp[(size_t)m * C] = acc[mt][tn][r] + bias;
      }
    }
  }
}

// ---------------- edge kernels (no max-shift, unrolled x8) ----------------

__global__ __launch_bounds__(256) void edge1_kernel(
    const float* __restrict__ xl, const float* __restrict__ xr,
    const float* __restrict__ att, const float* __restrict__ bias,
    const int* __restrict__ offsets, const int* __restrict__ csr_src,
    float* __restrict__ h, int N) {
  int node = blockIdx.x * 4 + (threadIdx.x >> 6);
  if (node >= N) return;
  int lane = threadIdx.x & 63;
  int c = lane * 2;
  float2 xri = *(const float2*)(xr + (size_t)node * 128 + c);
  float2 at  = *(const float2*)(att + c);
  int s0 = __builtin_amdgcn_readfirstlane(offsets[node]);
  int s1 = __builtin_amdgcn_readfirstlane(offsets[node + 1]);
  float l = 0.f, a0 = 0.f, a1 = 0.f;
  int e = s0;
  for (; e + 8 <= s1; e += 8) {
    int j[8];
#pragma unroll
    for (int u = 0; u < 8; u++) j[u] = __builtin_amdgcn_readfirstlane(csr_src[e + u]);
    float2 mv[8];
#pragma unroll
    for (int u = 0; u < 8; u++) mv[u] = *(const float2*)(xl + (size_t)j[u] * 128 + c);
    float q[8];
#pragma unroll
    for (int u = 0; u < 8; u++) {
      float e0 = mv[u].x + xri.x; e0 = fmaxf(e0, NSLOPE * e0);
      float e1 = mv[u].y + xri.y; e1 = fmaxf(e1, NSLOPE * e1);
      q[u] = fmaf(e0, at.x, e1 * at.y);
    }
#pragma unroll
    for (int d = 1; d < 16; d <<= 1)
#pragma unroll
      for (int u = 0; u < 8; u++) q[u] += __shfl_xor(q[u], d, 16);
#pragma unroll
    for (int u = 0; u < 8; u++) {
      float p = __expf(q[u]);
      l += p;
      a0 = fmaf(p, mv[u].x, a0);
      a1 = fmaf(p, mv[u].y, a1);
    }
  }
  for (; e < s1; e++) {
    int j = __builtin_amdgcn_readfirstlane(csr_src[e]);
    float2 msg = *(const float2*)(xl + (size_t)j * 128 + c);
    float e0 = msg.x + xri.x; e0 = fmaxf(e0, NSLOPE * e0);
    float e1 = msg.y + xri.y; e1 = fmaxf(e1, NSLOPE * e1);
    float p = fmaf(e0, at.x, e1 * at.y);
#pragma unroll
    for (int d = 1; d < 16; d <<= 1) p += __shfl_xor(p, d, 16);
    p = __expf(p);
    l += p;
    a0 = fmaf(p, msg.x, a0);
    a1 = fmaf(p, msg.y, a1);
  }
  float inv = 1.f / l;
  float2 bb = *(const float2*)(bias + c);
  float o0 = fmaxf(fmaf(a0, inv, bb.x), 0.f);
  float o1 = fmaxf(fmaf(a1, inv, bb.y), 0.f);
  *(float2*)(h + (size_t)node * 128 + c) = make_float2(o0, o1);
}

__global__ __launch_bounds__(256) void edge2_kernel(
    const float* __restrict__ xl, const float* __restrict__ xr,
    const float* __restrict__ att, const float* __restrict__ bias,
    const int* __restrict__ offsets, const int* __restrict__ csr_src,
    float* __restrict__ out, int N) {
  int node = blockIdx.x * 4 + (threadIdx.x >> 6);
  if (node >= N) return;
  int lane = threadIdx.x & 63;
  float xri = xr[(size_t)node * 64 + lane];
  float at  = att[lane];
  int s0 = __builtin_amdgcn_readfirstlane(offsets[node]);
  int s1 = __builtin_amdgcn_readfirstlane(offsets[node + 1]);
  float l = 0.f, a = 0.f;
  int e = s0;
  for (; e + 8 <= s1; e += 8) {
    int j[8];
#pragma unroll
    for (int u = 0; u < 8; u++) j[u] = __builtin_amdgcn_readfirstlane(csr_src[e + u]);
    float mv[8];
#pragma unroll
    for (int u = 0; u < 8; u++) mv[u] = xl[(size_t)j[u] * 64 + lane];
    float q[8];
#pragma unroll
    for (int u = 0; u < 8; u++) {
      float ee = mv[u] + xri; ee = fmaxf(ee, NSLOPE * ee);
      q[u] = ee * at;
    }
#pragma unroll
    for (int d = 1; d < 64; d <<= 1)
#pragma unroll
      for (int u = 0; u < 8; u++) q[u] += __shfl_xor(q[u], d);
#pragma unroll
    for (int u = 0; u < 8; u++) {
      float p = __expf(q[u]);
      l += p;
      a = fmaf(p, mv[u], a);
    }
  }
  for (; e < s1; e++) {
    int j = __builtin_amdgcn_readfirstlane(csr_src[e]);
    float msg = xl[(size_t)j * 64 + lane];
    float ee = msg + xri; ee = fmaxf(ee, NSLOPE * ee);
    float p = ee * at;
#pragma unroll
    for (int d = 1; d < 64; d <<= 1) p += __shfl_xor(p, d);
    p = __expf(p);
    l += p;
    a = fmaf(p, msg, a);
  }
  out[(size_t)node * 64 + lane] = fmaf(a, 1.f / l, bias[lane]);
}

extern "C" void kernel_launch(void* const* d_in, const int* in_sizes, int n_in,
                              void* d_out, int out_size, void* d_ws, size_t ws_size,
                              hipStream_t stream) {
  const float* x    = (const float*)d_in[0];
  const int*   ei   = (const int*)d_in[1];
  const float* Wl1  = (const float*)d_in[2];
  const float* bl1  = (const float*)d_in[3];
  const float* Wr1  = (const float*)d_in[4];
  const float* br1  = (const float*)d_in[5];
  const float* att1 = (const float*)d_in[6];
  const float* bias1= (const float*)d_in[7];
  const float* Wl2  = (const float*)d_in[8];
  const float* bl2  = (const float*)d_in[9];
  const float* Wr2  = (const float*)d_in[10];
  const float* br2  = (const float*)d_in[11];
  const float* att2 = (const float*)d_in[12];
  const float* bias2= (const float*)d_in[13];
  float* out = (float*)d_out;

  const int N = in_sizes[0] / 128;
  const int E = in_sizes[1] / 2;
  const int Etot = E + N;
  const int* srcv = ei;
  const int* dstv = ei + E;

  char* ws = (char*)d_ws;
  size_t off = 0;
  auto alloc = [&](size_t bytes) -> void* {
    void* p = ws + off;
    off = (off + bytes + 255) & ~(size_t)255;
    return p;
  };
  int* offsets     = (int*)alloc((size_t)(N + 1) * 4);
  int* cursor      = (int*)alloc((size_t)N * 4);
  int* counts      = (int*)alloc((size_t)N * 4);
  int* blockSums   = (int*)alloc(256 * 4);
  int* blockPrefix = (int*)alloc(256 * 4);
  int* csr_src     = (int*)alloc((size_t)Etot * 4);
  unsigned short* B1hi = (unsigned short*)alloc(16 * 4 * 64 * 8 * 2);
  unsigned short* B1lo = (unsigned short*)alloc(16 * 4 * 64 * 8 * 2);
  unsigned short* B2hi = (unsigned short*)alloc(8 * 4 * 64 * 8 * 2);
  unsigned short* B2lo = (unsigned short*)alloc(8 * 4 * 64 * 8 * 2);
  float* xl1 = (float*)alloc((size_t)N * 128 * 4);
  float* xr1 = (float*)alloc((size_t)N * 128 * 4);
  float* hbuf= (float*)alloc((size_t)N * 128 * 4);
  float* xl2 = xl1;  // reuse (xl1/xr1 dead after edge1)
  float* xr2 = xr1;
  (void)ws_size; (void)n_in; (void)out_size;

  int nb = (N + 1023) / 1024;
  int mb = (N + 127) / 128;

  zero_counts_kernel<<<(N + 255) / 256, 256, 0, stream>>>(counts, N);
  count_kernel<<<(E / 4 + 255) / 256, 256, 0, stream>>>(dstv, counts, E);
  scanA_kernel<<<nb, 256, 0, stream>>>(counts, offsets, blockSums, N);
  scanB_kernel<<<1, 64, 0, stream>>>(blockSums, blockPrefix, offsets, nb, N);
  scanC_kernel<<<(N + 255) / 256, 256, 0, stream>>>(blockPrefix, counts, offsets, cursor, csr_src, N);
  scatter_kernel<<<(E / 4 + 255) / 256, 256, 0, stream>>>(srcv, dstv, cursor, csr_src, E);

  prep_b_kernel<<<16, 256, 0, stream>>>(Wl1, Wr1, 128, B1hi, B1lo, 16 * 4 * 64);
  prep_b_kernel<<<8, 256, 0, stream>>>(Wl2, Wr2, 64, B2hi, B2lo, 8 * 4 * 64);

  gemm_mfma_kernel<<<dim3(mb, 4), 256, 0, stream>>>(x, B1hi, B1lo, bl1, br1, xl1, xr1, 128, N);
  edge1_kernel<<<(N + 3) / 4, 256, 0, stream>>>(xl1, xr1, att1, bias1, offsets, csr_src, hbuf, N);
  gemm_mfma_kernel<<<dim3(mb, 2), 256, 0, stream>>>(hbuf, B2hi, B2lo, bl2, br2, xl2, xr2, 64, N);
  edge2_kernel<<<(N + 3) / 4, 256, 0, stream>>>(xl2, xr2, att2, bias2, offsets, csr_src, out, N);
}

// Round 5
// 336.957 us; speedup vs baseline: 1.3125x; 1.0646x over previous
//
#include <hip/hip_runtime.h>
#include <hip/hip_bf16.h>
#include <math.h>

// GATv2 x2 layers. N=50000, E=800000 (+N self loops), D_in=128, H=4, Hd=32 (HC=128), D_out=64.
// R2: GEMMs -> bf16x3 split MFMA, W pre-swizzled to fragment layout.
// R3: no-max-shift softmax (scores tiny; shift-invariant), self-loop slot via scanC.
// R5: edge kernels: butterfly multi-reduce (8 dots in 10 shuffles + 8 bpermute + 1 exp
//     vs 48 shuffles + 8 exp) -- DS-pipe was the ~65us floor. scatter/count x8 ILP.

#define NSLOPE 0.2f

typedef __attribute__((ext_vector_type(8))) short short8;
typedef __attribute__((ext_vector_type(4))) float f32x4;

__device__ inline unsigned short f2bf(float f) {
  unsigned int u = __float_as_uint(f);
  u += 0x7fff + ((u >> 16) & 1);   // round-to-nearest-even
  return (unsigned short)(u >> 16);
}
__device__ inline float bf2f(unsigned short h) {
  return __uint_as_float(((unsigned int)h) << 16);
}

// butterfly pair-merge: result(l) = sum over {l, l^m} of (l&m ? qb : qa)
__device__ inline float merge2(float qa, float qb, int m, int lane) {
  bool hi = (lane & m) != 0;
  float sel = hi ? qb : qa;
  float oth = hi ? qa : qb;
  return sel + __shfl_xor(oth, m);
}

// ---------------- CSR build ----------------

__global__ void zero_counts_kernel(int* __restrict__ counts, int n) {
  int i = blockIdx.x * 256 + threadIdx.x;
  if (i < n) counts[i] = 0;
}

__global__ void count_kernel(const int* __restrict__ dst, int* __restrict__ counts, int E) {
  int e = (blockIdx.x * 256 + threadIdx.x) * 8;
  if (e + 8 <= E) {
    int d[8];
#pragma unroll
    for (int u = 0; u < 8; u++) d[u] = dst[e + u];
#pragma unroll
    for (int u = 0; u < 8; u++) atomicAdd(&counts[d[u]], 1);
  } else {
    for (; e < E; e++) atomicAdd(&counts[dst[e]], 1);
  }
}

__global__ __launch_bounds__(256) void scanA_kernel(const int* __restrict__ counts,
                                                    int* __restrict__ offsets,
                                                    int* __restrict__ blockSums, int N) {
  int t = threadIdx.x;
  int lane = t & 63, wv = t >> 6;
  int g0 = blockIdx.x * 1024 + t * 4;
  int v[4];
#pragma unroll
  for (int u = 0; u < 4; u++) {
    int i = g0 + u;
    v[u] = (i < N) ? (counts[i] + 1) : 0;
  }
  int s = v[0] + v[1] + v[2] + v[3];
  int inc = s;
#pragma unroll
  for (int d = 1; d < 64; d <<= 1) {
    int n = __shfl_up(inc, d);
    if (lane >= d) inc += n;
  }
  __shared__ int wsum[4];
  if (lane == 63) wsum[wv] = inc;
  __syncthreads();
  int wprefix = 0;
#pragma unroll
  for (int w = 0; w < 4; w++)
    if (w < wv) wprefix += wsum[w];
  int run = wprefix + inc - s;
#pragma unroll
  for (int u = 0; u < 4; u++) {
    int i = g0 + u;
    if (i < N) offsets[i] = run;
    run += v[u];
  }
  if (t == 255) blockSums[blockIdx.x] = wprefix + inc;
}

__global__ void scanB_kernel(const int* __restrict__ blockSums, int* __restrict__ blockPrefix,
                             int* __restrict__ offsets, int nb, int N) {
  int lane = threadIdx.x;  // 64 threads
  int carry = 0;
  for (int base = 0; base < nb; base += 64) {
    int i = base + lane;
    int v = (i < nb) ? blockSums[i] : 0;
    int inc = v;
#pragma unroll
    for (int d = 1; d < 64; d <<= 1) {
      int n = __shfl_up(inc, d);
      if (lane >= d) inc += n;
    }
    if (i < nb) blockPrefix[i] = carry + inc - v;
    carry += __shfl(inc, 63);
  }
  if (lane == 0) offsets[N] = carry;
}

__global__ void scanC_kernel(const int* __restrict__ blockPrefix, const int* __restrict__ counts,
                             int* __restrict__ offsets, int* __restrict__ cursor,
                             int* __restrict__ csr_src, int N) {
  int i = blockIdx.x * 256 + threadIdx.x;
  if (i < N) {
    int v = offsets[i] + blockPrefix[i >> 10];
    offsets[i] = v;
    cursor[i] = v;
    csr_src[v + counts[i]] = i;  // self loop occupies the segment's last slot
  }
}

__global__ void scatter_kernel(const int* __restrict__ srcv, const int* __restrict__ dstv,
                               int* __restrict__ cursor, int* __restrict__ csr_src, int E) {
  int e = (blockIdx.x * 256 + threadIdx.x) * 8;
  if (e + 8 <= E) {
    int d[8], s[8], p[8];
#pragma unroll
    for (int u = 0; u < 8; u++) { d[u] = dstv[e + u]; s[u] = srcv[e + u]; }
#pragma unroll
    for (int u = 0; u < 8; u++) p[u] = atomicAdd(&cursor[d[u]], 1);
#pragma unroll
    for (int u = 0; u < 8; u++) csr_src[p[u]] = s[u];
  } else {
    for (; e < E; e++) {
      int pos = atomicAdd(&cursor[dstv[e]], 1);
      csr_src[pos] = srcv[e];
    }
  }
}

// ---------------- MFMA GEMM (bf16x3 split) ----------------

__global__ __launch_bounds__(256) void prep_b_kernel(const float* __restrict__ Wl,
    const float* __restrict__ Wr, int C,
    unsigned short* __restrict__ Bhi, unsigned short* __restrict__ Blo, int total) {
  int t = blockIdx.x * 256 + threadIdx.x;
  if (t >= total) return;
  int lane = t & 63;
  int kt = (t >> 6) & 3;
  int tn = t >> 8;
  int n = tn * 16 + (lane & 15);
  int k0 = kt * 32 + ((lane >> 4) * 8);
  const float* W = (n < C) ? (Wl + n) : (Wr + (n - C));
  size_t base = ((size_t)(tn * 4 + kt) * 64 + lane) * 8;
#pragma unroll
  for (int j = 0; j < 8; j++) {
    float v = W[(size_t)(k0 + j) * C];
    unsigned short hi = f2bf(v);
    Bhi[base + j] = hi;
    Blo[base + j] = f2bf(v - bf2f(hi));
  }
}

__global__ __launch_bounds__(256) void gemm_mfma_kernel(const float* __restrict__ A,
    const unsigned short* __restrict__ Bhi, const unsigned short* __restrict__ Blo,
    const float* __restrict__ bl, const float* __restrict__ br,
    float* __restrict__ xl, float* __restrict__ xr, int C, int M) {
  __shared__ unsigned short sBh[16 * 512];
  __shared__ unsigned short sBl[16 * 512];
  int t = threadIdx.x;
  int g = blockIdx.y;
  {
    const float4* srcH = (const float4*)(Bhi + (size_t)g * 8192);
    const float4* srcL = (const float4*)(Blo + (size_t)g * 8192);
    float4* dH = (float4*)sBh;
    float4* dL = (float4*)sBl;
#pragma unroll
    for (int i = 0; i < 4; i++) {
      dH[t + 256 * i] = srcH[t + 256 * i];
      dL[t + 256 * i] = srcL[t + 256 * i];
    }
  }
  __syncthreads();
  int w = t >> 6, l = t & 63;
  int m_base = blockIdx.x * 128 + w * 32;
  int mrow = l & 15;
  int kq = l >> 4;
  f32x4 acc[2][4];
#pragma unroll
  for (int mt = 0; mt < 2; mt++)
#pragma unroll
    for (int tn = 0; tn < 4; tn++) acc[mt][tn] = (f32x4){0.f, 0.f, 0.f, 0.f};

#pragma unroll
  for (int kt = 0; kt < 4; kt++) {
    short8 ah[2], al[2];
#pragma unroll
    for (int mt = 0; mt < 2; mt++) {
      int m = m_base + mt * 16 + mrow;
      m = (m < M) ? m : (M - 1);
      const float* pa = A + (size_t)m * 128 + kt * 32 + kq * 8;
      float4 v0 = *(const float4*)pa;
      float4 v1 = *(const float4*)(pa + 4);
      float f[8] = {v0.x, v0.y, v0.z, v0.w, v1.x, v1.y, v1.z, v1.w};
#pragma unroll
      for (int j = 0; j < 8; j++) {
        unsigned short hi = f2bf(f[j]);
        ah[mt][j] = (short)hi;
        al[mt][j] = (short)f2bf(f[j] - bf2f(hi));
      }
    }
#pragma unroll
    for (int tn = 0; tn < 4; tn++) {
      int off = ((tn * 4 + kt) * 64 + l) * 8;
      short8 bh = *(const short8*)(sBh + off);
      short8 blo = *(const short8*)(sBl + off);
#pragma unroll
      for (int mt = 0; mt < 2; mt++) {
        acc[mt][tn] = __builtin_amdgcn_mfma_f32_16x16x32_bf16(ah[mt], bh, acc[mt][tn], 0, 0, 0);
        acc[mt][tn] = __builtin_amdgcn_mfma_f32_16x16x32_bf16(ah[mt], blo, acc[mt][tn], 0, 0, 0);
        acc[mt][tn] = __builtin_amdgcn_mfma_f32_16x16x32_bf16(al[mt], bh, acc[mt][tn], 0, 0, 0);
      }
    }
  }
#pragma unroll
  for (int tn = 0; tn < 4; tn++) {
    int n = g * 64 + tn * 16 + mrow;
    float bias = (n < C) ? bl[n] : br[n - C];
    float* outp = (n < C) ? (xl + n) : (xr + (n - C));
#pragma unroll
    for (int mt = 0; mt < 2; mt++) {
#pragma unroll
      for (int r = 0; r < 4; r++) {
        int m = m_base + mt * 16 + kq * 4 + r;
        if (m < M) outp[(size_t)m * C] = acc[mt][tn][r] + bias;
      }
    }
  }
}

// ---------------- edge kernels (butterfly multi-reduce) ----------------

// edge1: one wave per dst node. 128 ch -> 2/lane. head = 16-lane group.
__global__ __launch_bounds__(256) void edge1_kernel(
    const float* __restrict__ xl, const float* __restrict__ xr,
    const float* __restrict__ att, const float* __restrict__ bias,
    const int* __restrict__ offsets, const int* __restrict__ csr_src,
    float* __restrict__ h, int N) {
  int node = blockIdx.x * 4 + (threadIdx.x >> 6);
  if (node >= N) return;
  int lane = threadIdx.x & 63;
  int c = lane * 2;
  float2 xri = *(const float2*)(xr + (size_t)node * 128 + c);
  float2 at  = *(const float2*)(att + c);
  int s0 = __builtin_amdgcn_readfirstlane(offsets[node]);
  int s1 = __builtin_amdgcn_readfirstlane(offsets[node + 1]);
  float l = 0.f, a0 = 0.f, a1 = 0.f;
  int base16 = lane & 48;  // start of this head's 16-lane group
  int e = s0;
  for (; e + 8 <= s1; e += 8) {
    int j[8];
#pragma unroll
    for (int u = 0; u < 8; u++) j[u] = __builtin_amdgcn_readfirstlane(csr_src[e + u]);
    float2 mv[8];
#pragma unroll
    for (int u = 0; u < 8; u++) mv[u] = *(const float2*)(xl + (size_t)j[u] * 128 + c);
    float q[8];
#pragma unroll
    for (int u = 0; u < 8; u++) {
      float e0 = mv[u].x + xri.x; e0 = fmaxf(e0, NSLOPE * e0);
      float e1 = mv[u].y + xri.y; e1 = fmaxf(e1, NSLOPE * e1);
      q[u] = fmaf(e0, at.x, e1 * at.y);
    }
    // butterfly multi-reduce over the 16-lane head group: value index lands at lane&7
    float v0 = merge2(q[0], q[1], 1, lane);
    float v1 = merge2(q[2], q[3], 1, lane);
    float v2 = merge2(q[4], q[5], 1, lane);
    float v3 = merge2(q[6], q[7], 1, lane);
    float w0 = merge2(v0, v1, 2, lane);
    float w1 = merge2(v2, v3, 2, lane);
    float uu = merge2(w0, w1, 4, lane);
    uu += __shfl_xor(uu, 8);       // full 16-lane sum of q[lane&7]
    float p = __expf(uu);
    float cb[8];
#pragma unroll
    for (int u = 0; u < 8; u++) cb[u] = __shfl(p, base16 + u);
#pragma unroll
    for (int u = 0; u < 8; u++) {
      l += cb[u];
      a0 = fmaf(cb[u], mv[u].x, a0);
      a1 = fmaf(cb[u], mv[u].y, a1);
    }
  }
  for (; e < s1; e++) {
    int j = __builtin_amdgcn_readfirstlane(csr_src[e]);
    float2 msg = *(const float2*)(xl + (size_t)j * 128 + c);
    float e0 = msg.x + xri.x; e0 = fmaxf(e0, NSLOPE * e0);
    float e1 = msg.y + xri.y; e1 = fmaxf(e1, NSLOPE * e1);
    float p = fmaf(e0, at.x, e1 * at.y);
#pragma unroll
    for (int d = 1; d < 16; d <<= 1) p += __shfl_xor(p, d, 16);
    p = __expf(p);
    l += p;
    a0 = fmaf(p, msg.x, a0);
    a1 = fmaf(p, msg.y, a1);
  }
  float inv = 1.f / l;
  float2 bb = *(const float2*)(bias + c);
  float o0 = fmaxf(fmaf(a0, inv, bb.x), 0.f);
  float o1 = fmaxf(fmaf(a1, inv, bb.y), 0.f);
  *(float2*)(h + (size_t)node * 128 + c) = make_float2(o0, o1);
}

// edge2: one wave per dst node. 64 ch -> 1/lane, 1 head (64-wide reduce).
__global__ __launch_bounds__(256) void edge2_kernel(
    const float* __restrict__ xl, const float* __restrict__ xr,
    const float* __restrict__ att, const float* __restrict__ bias,
    const int* __restrict__ offsets, const int* __restrict__ csr_src,
    float* __restrict__ out, int N) {
  int node = blockIdx.x * 4 + (threadIdx.x >> 6);
  if (node >= N) return;
  int lane = threadIdx.x & 63;
  float xri = xr[(size_t)node * 64 + lane];
  float at  = att[lane];
  int s0 = __builtin_amdgcn_readfirstlane(offsets[node]);
  int s1 = __builtin_amdgcn_readfirstlane(offsets[node + 1]);
  float l = 0.f, a = 0.f;
  int base8 = lane & 56;  // start of this lane's 8-group
  int e = s0;
  for (; e + 8 <= s1; e += 8) {
    int j[8];
#pragma unroll
    for (int u = 0; u < 8; u++) j[u] = __builtin_amdgcn_readfirstlane(csr_src[e + u]);
    float mv[8];
#pragma unroll
    for (int u = 0; u < 8; u++) mv[u] = xl[(size_t)j[u] * 64 + lane];
    float q[8];
#pragma unroll
    for (int u = 0; u < 8; u++) {
      float ee = mv[u] + xri; ee = fmaxf(ee, NSLOPE * ee);
      q[u] = ee * at;
    }
    // butterfly multi-reduce across 64 lanes: value index lands at lane&7
    float v0 = merge2(q[0], q[1], 1, lane);
    float v1 = merge2(q[2], q[3], 1, lane);
    float v2 = merge2(q[4], q[5], 1, lane);
    float v3 = merge2(q[6], q[7], 1, lane);
    float w0 = merge2(v0, v1, 2, lane);
    float w1 = merge2(v2, v3, 2, lane);
    float uu = merge2(w0, w1, 4, lane);
    uu += __shfl_xor(uu, 8);
    uu += __shfl_xor(uu, 16);
    uu += __shfl_xor(uu, 32);      // full 64-lane sum of q[lane&7]
    float p = __expf(uu);
    float cb[8];
#pragma unroll
    for (int u = 0; u < 8; u++) cb[u] = __shfl(p, base8 + u);
#pragma unroll
    for (int u = 0; u < 8; u++) {
      l += cb[u];
      a = fmaf(cb[u], mv[u], a);
    }
  }
  for (; e < s1; e++) {
    int j = __builtin_amdgcn_readfirstlane(csr_src[e]);
    float msg = xl[(size_t)j * 64 + lane];
    float ee = msg + xri; ee = fmaxf(ee, NSLOPE * ee);
    float p = ee * at;
#pragma unroll
    for (int d = 1; d < 64; d <<= 1) p += __shfl_xor(p, d);
    p = __expf(p);
    l += p;
    a = fmaf(p, msg, a);
  }
  out[(size_t)node * 64 + lane] = fmaf(a, 1.f / l, bias[lane]);
}

extern "C" void kernel_launch(void* const* d_in, const int* in_sizes, int n_in,
                              void* d_out, int out_size, void* d_ws, size_t ws_size,
                              hipStream_t stream) {
  const float* x    = (const float*)d_in[0];
  const int*   ei   = (const int*)d_in[1];
  const float* Wl1  = (const float*)d_in[2];
  const float* bl1  = (const float*)d_in[3];
  const float* Wr1  = (const float*)d_in[4];
  const float* br1  = (const float*)d_in[5];
  const float* att1 = (const float*)d_in[6];
  const float* bias1= (const float*)d_in[7];
  const float* Wl2  = (const float*)d_in[8];
  const float* bl2  = (const float*)d_in[9];
  const float* Wr2  = (const float*)d_in[10];
  const float* br2  = (const float*)d_in[11];
  const float* att2 = (const float*)d_in[12];
  const float* bias2= (const float*)d_in[13];
  float* out = (float*)d_out;

  const int N = in_sizes[0] / 128;
  const int E = in_sizes[1] / 2;
  const int Etot = E + N;
  const int* srcv = ei;
  const int* dstv = ei + E;

  char* ws = (char*)d_ws;
  size_t off = 0;
  auto alloc = [&](size_t bytes) -> void* {
    void* p = ws + off;
    off = (off + bytes + 255) & ~(size_t)255;
    return p;
  };
  int* offsets     = (int*)alloc((size_t)(N + 1) * 4);
  int* cursor      = (int*)alloc((size_t)N * 4);
  int* counts      = (int*)alloc((size_t)N * 4);
  int* blockSums   = (int*)alloc(256 * 4);
  int* blockPrefix = (int*)alloc(256 * 4);
  int* csr_src     = (int*)alloc((size_t)Etot * 4);
  unsigned short* B1hi = (unsigned short*)alloc(16 * 4 * 64 * 8 * 2);
  unsigned short* B1lo = (unsigned short*)alloc(16 * 4 * 64 * 8 * 2);
  unsigned short* B2hi = (unsigned short*)alloc(8 * 4 * 64 * 8 * 2);
  unsigned short* B2lo = (unsigned short*)alloc(8 * 4 * 64 * 8 * 2);
  float* xl1 = (float*)alloc((size_t)N * 128 * 4);
  float* xr1 = (float*)alloc((size_t)N * 128 * 4);
  float* hbuf= (float*)alloc((size_t)N * 128 * 4);
  float* xl2 = xl1;  // reuse (xl1/xr1 dead after edge1)
  float* xr2 = xr1;
  (void)ws_size; (void)n_in; (void)out_size;

  int nb = (N + 1023) / 1024;
  int mb = (N + 127) / 128;

  zero_counts_kernel<<<(N + 255) / 256, 256, 0, stream>>>(counts, N);
  count_kernel<<<(E / 8 + 255) / 256, 256, 0, stream>>>(dstv, counts, E);
  scanA_kernel<<<nb, 256, 0, stream>>>(counts, offsets, blockSums, N);
  scanB_kernel<<<1, 64, 0, stream>>>(blockSums, blockPrefix, offsets, nb, N);
  scanC_kernel<<<(N + 255) / 256, 256, 0, stream>>>(blockPrefix, counts, offsets, cursor, csr_src, N);
  scatter_kernel<<<(E / 8 + 255) / 256, 256, 0, stream>>>(srcv, dstv, cursor, csr_src, E);

  prep_b_kernel<<<16, 256, 0, stream>>>(Wl1, Wr1, 128, B1hi, B1lo, 16 * 4 * 64);
  prep_b_kernel<<<8, 256, 0, stream>>>(Wl2, Wr2, 64, B2hi, B2lo, 8 * 4 * 64);

  gemm_mfma_kernel<<<dim3(mb, 4), 256, 0, stream>>>(x, B1hi, B1lo, bl1, br1, xl1, xr1, 128, N);
  edge1_kernel<<<(N + 3) / 4, 256, 0, stream>>>(xl1, xr1, att1, bias1, offsets, csr_src, hbuf, N);
  gemm_mfma_kernel<<<dim3(mb, 2), 256, 0, stream>>>(hbuf, B2hi, B2lo, bl2, br2, xl2, xr2, 64, N);
  edge2_kernel<<<(N + 3) / 4, 256, 0, stream>>>(xl2, xr2, att2, bias2, offsets, csr_src, out, N);
}

// Round 6
// 308.659 us; speedup vs baseline: 1.4328x; 1.0917x over previous
//
#include <hip/hip_runtime.h>
#include <hip/hip_bf16.h>
#include <math.h>

// GATv2 x2 layers. N=50000, E=800000 (+N self loops), D_in=128, H=4, Hd=32 (HC=128), D_out=64.
// R2: GEMMs -> bf16x3 split MFMA, W pre-swizzled to fragment layout.
// R3: no-max-shift softmax (scores tiny; shift-invariant), self-loop slot via scanC.
// R5: butterfly multi-reduce in edge kernels; scatter/count x8 ILP.
// R6: xl1 stored bf16 (edge1 gather bytes halved: 435->218 MB requested);
//     masked final group (q=-1e30 -> exp=0) kills the serial remainder loop;
//     counts zeroed via hipMemsetAsync.

#define NSLOPE 0.2f

typedef __attribute__((ext_vector_type(8))) short short8;
typedef __attribute__((ext_vector_type(4))) float f32x4;

__device__ inline unsigned short f2bf(float f) {
  unsigned int u = __float_as_uint(f);
  u += 0x7fff + ((u >> 16) & 1);   // round-to-nearest-even
  return (unsigned short)(u >> 16);
}
__device__ inline float bf2f(unsigned short h) {
  return __uint_as_float(((unsigned int)h) << 16);
}

// butterfly pair-merge: result(l) = sum over {l, l^m} of (l&m ? qb : qa)
__device__ inline float merge2(float qa, float qb, int m, int lane) {
  bool hi = (lane & m) != 0;
  float sel = hi ? qb : qa;
  float oth = hi ? qa : qb;
  return sel + __shfl_xor(oth, m);
}

// ---------------- CSR build ----------------

__global__ void count_kernel(const int* __restrict__ dst, int* __restrict__ counts, int E) {
  int e = (blockIdx.x * 256 + threadIdx.x) * 8;
  if (e + 8 <= E) {
    int d[8];
#pragma unroll
    for (int u = 0; u < 8; u++) d[u] = dst[e + u];
#pragma unroll
    for (int u = 0; u < 8; u++) atomicAdd(&counts[d[u]], 1);
  } else {
    for (; e < E; e++) atomicAdd(&counts[dst[e]], 1);
  }
}

__global__ __launch_bounds__(256) void scanA_kernel(const int* __restrict__ counts,
                                                    int* __restrict__ offsets,
                                                    int* __restrict__ blockSums, int N) {
  int t = threadIdx.x;
  int lane = t & 63, wv = t >> 6;
  int g0 = blockIdx.x * 1024 + t * 4;
  int v[4];
#pragma unroll
  for (int u = 0; u < 4; u++) {
    int i = g0 + u;
    v[u] = (i < N) ? (counts[i] + 1) : 0;
  }
  int s = v[0] + v[1] + v[2] + v[3];
  int inc = s;
#pragma unroll
  for (int d = 1; d < 64; d <<= 1) {
    int n = __shfl_up(inc, d);
    if (lane >= d) inc += n;
  }
  __shared__ int wsum[4];
  if (lane == 63) wsum[wv] = inc;
  __syncthreads();
  int wprefix = 0;
#pragma unroll
  for (int w = 0; w < 4; w++)
    if (w < wv) wprefix += wsum[w];
  int run = wprefix + inc - s;
#pragma unroll
  for (int u = 0; u < 4; u++) {
    int i = g0 + u;
    if (i < N) offsets[i] = run;
    run += v[u];
  }
  if (t == 255) blockSums[blockIdx.x] = wprefix + inc;
}

__global__ void scanB_kernel(const int* __restrict__ blockSums, int* __restrict__ blockPrefix,
                             int* __restrict__ offsets, int nb, int N) {
  int lane = threadIdx.x;  // 64 threads
  int carry = 0;
  for (int base = 0; base < nb; base += 64) {
    int i = base + lane;
    int v = (i < nb) ? blockSums[i] : 0;
    int inc = v;
#pragma unroll
    for (int d = 1; d < 64; d <<= 1) {
      int n = __shfl_up(inc, d);
      if (lane >= d) inc += n;
    }
    if (i < nb) blockPrefix[i] = carry + inc - v;
    carry += __shfl(inc, 63);
  }
  if (lane == 0) offsets[N] = carry;
}

__global__ void scanC_kernel(const int* __restrict__ blockPrefix, const int* __restrict__ counts,
                             int* __restrict__ offsets, int* __restrict__ cursor,
                             int* __restrict__ csr_src, int N) {
  int i = blockIdx.x * 256 + threadIdx.x;
  if (i < N) {
    int v = offsets[i] + blockPrefix[i >> 10];
    offsets[i] = v;
    cursor[i] = v;
    csr_src[v + counts[i]] = i;  // self loop occupies the segment's last slot
  }
}

__global__ void scatter_kernel(const int* __restrict__ srcv, const int* __restrict__ dstv,
                               int* __restrict__ cursor, int* __restrict__ csr_src, int E) {
  int e = (blockIdx.x * 256 + threadIdx.x) * 8;
  if (e + 8 <= E) {
    int d[8], s[8], p[8];
#pragma unroll
    for (int u = 0; u < 8; u++) { d[u] = dstv[e + u]; s[u] = srcv[e + u]; }
#pragma unroll
    for (int u = 0; u < 8; u++) p[u] = atomicAdd(&cursor[d[u]], 1);
#pragma unroll
    for (int u = 0; u < 8; u++) csr_src[p[u]] = s[u];
  } else {
    for (; e < E; e++) {
      int pos = atomicAdd(&cursor[dstv[e]], 1);
      csr_src[pos] = srcv[e];
    }
  }
}

// ---------------- MFMA GEMM (bf16x3 split) ----------------

__global__ __launch_bounds__(256) void prep_b_kernel(const float* __restrict__ Wl,
    const float* __restrict__ Wr, int C,
    unsigned short* __restrict__ Bhi, unsigned short* __restrict__ Blo, int total) {
  int t = blockIdx.x * 256 + threadIdx.x;
  if (t >= total) return;
  int lane = t & 63;
  int kt = (t >> 6) & 3;
  int tn = t >> 8;
  int n = tn * 16 + (lane & 15);
  int k0 = kt * 32 + ((lane >> 4) * 8);
  const float* W = (n < C) ? (Wl + n) : (Wr + (n - C));
  size_t base = ((size_t)(tn * 4 + kt) * 64 + lane) * 8;
#pragma unroll
  for (int j = 0; j < 8; j++) {
    float v = W[(size_t)(k0 + j) * C];
    unsigned short hi = f2bf(v);
    Bhi[base + j] = hi;
    Blo[base + j] = f2bf(v - bf2f(hi));
  }
}

// BF: xl output stored as bf16 (for edge1's gather); xr always f32.
template<bool BF>
__global__ __launch_bounds__(256) void gemm_mfma_kernel(const float* __restrict__ A,
    const unsigned short* __restrict__ Bhi, const unsigned short* __restrict__ Blo,
    const float* __restrict__ bl, const float* __restrict__ br,
    void* __restrict__ xl_out, float* __restrict__ xr, int C, int M) {
  __shared__ unsigned short sBh[16 * 512];
  __shared__ unsigned short sBl[16 * 512];
  int t = threadIdx.x;
  int g = blockIdx.y;
  {
    const float4* srcH = (const float4*)(Bhi + (size_t)g * 8192);
    const float4* srcL = (const float4*)(Blo + (size_t)g * 8192);
    float4* dH = (float4*)sBh;
    float4* dL = (float4*)sBl;
#pragma unroll
    for (int i = 0; i < 4; i++) {
      dH[t + 256 * i] = srcH[t + 256 * i];
      dL[t + 256 * i] = srcL[t + 256 * i];
    }
  }
  __syncthreads();
  int w = t >> 6, l = t & 63;
  int m_base = blockIdx.x * 128 + w * 32;
  int mrow = l & 15;
  int kq = l >> 4;
  f32x4 acc[2][4];
#pragma unroll
  for (int mt = 0; mt < 2; mt++)
#pragma unroll
    for (int tn = 0; tn < 4; tn++) acc[mt][tn] = (f32x4){0.f, 0.f, 0.f, 0.f};

#pragma unroll
  for (int kt = 0; kt < 4; kt++) {
    short8 ah[2], al[2];
#pragma unroll
    for (int mt = 0; mt < 2; mt++) {
      int m = m_base + mt * 16 + mrow;
      m = (m < M) ? m : (M - 1);
      const float* pa = A + (size_t)m * 128 + kt * 32 + kq * 8;
      float4 v0 = *(const float4*)pa;
      float4 v1 = *(const float4*)(pa + 4);
      float f[8] = {v0.x, v0.y, v0.z, v0.w, v1.x, v1.y, v1.z, v1.w};
#pragma unroll
      for (int j = 0; j < 8; j++) {
        unsigned short hi = f2bf(f[j]);
        ah[mt][j] = (short)hi;
        al[mt][j] = (short)f2bf(f[j] - bf2f(hi));
      }
    }
#pragma unroll
    for (int tn = 0; tn < 4; tn++) {
      int off = ((tn * 4 + kt) * 64 + l) * 8;
      short8 bh = *(const short8*)(sBh + off);
      short8 blo = *(const short8*)(sBl + off);
#pragma unroll
      for (int mt = 0; mt < 2; mt++) {
        acc[mt][tn] = __builtin_amdgcn_mfma_f32_16x16x32_bf16(ah[mt], bh, acc[mt][tn], 0, 0, 0);
        acc[mt][tn] = __builtin_amdgcn_mfma_f32_16x16x32_bf16(ah[mt], blo, acc[mt][tn], 0, 0, 0);
        acc[mt][tn] = __builtin_amdgcn_mfma_f32_16x16x32_bf16(al[mt], bh, acc[mt][tn], 0, 0, 0);
      }
    }
  }
#pragma unroll
  for (int tn = 0; tn < 4; tn++) {
    int n = g * 64 + tn * 16 + mrow;
    float bias = (n < C) ? bl[n] : br[n - C];
#pragma unroll
    for (int mt = 0; mt < 2; mt++) {
#pragma unroll
      for (int r = 0; r < 4; r++) {
        int m = m_base + mt * 16 + kq * 4 + r;
        if (m < M) {
          float v = acc[mt][tn][r] + bias;
          if (n < C) {
            if (BF) ((unsigned short*)xl_out)[(size_t)m * C + n] = f2bf(v);
            else    ((float*)xl_out)[(size_t)m * C + n] = v;
          } else {
            xr[(size_t)m * C + (n - C)] = v;
          }
        }
      }
    }
  }
}

// ---------------- edge kernels (butterfly multi-reduce, masked tail group) ----------------

// edge1: one wave per dst node. 128 ch -> 2/lane (bf16 gather). head = 16-lane group.
__global__ __launch_bounds__(256) void edge1_kernel(
    const unsigned short* __restrict__ xl, const float* __restrict__ xr,
    const float* __restrict__ att, const float* __restrict__ bias,
    const int* __restrict__ offsets, const int* __restrict__ csr_src,
    float* __restrict__ h, int N) {
  int node = blockIdx.x * 4 + (threadIdx.x >> 6);
  if (node >= N) return;
  int lane = threadIdx.x & 63;
  int c = lane * 2;
  float2 xri = *(const float2*)(xr + (size_t)node * 128 + c);
  float2 at  = *(const float2*)(att + c);
  int s0 = __builtin_amdgcn_readfirstlane(offsets[node]);
  int s1 = __builtin_amdgcn_readfirstlane(offsets[node + 1]);
  int s1m1 = s1 - 1;
  float l = 0.f, a0 = 0.f, a1 = 0.f;
  int base16 = lane & 48;  // start of this head's 16-lane group
  for (int e = s0; e < s1; e += 8) {
    int j[8];
#pragma unroll
    for (int u = 0; u < 8; u++) {
      int ee = e + u;
      j[u] = __builtin_amdgcn_readfirstlane(csr_src[ee < s1 ? ee : s1m1]);
    }
    float2 mv[8];
#pragma unroll
    for (int u = 0; u < 8; u++) {
      unsigned int pk = *(const unsigned int*)(xl + (size_t)j[u] * 128 + c);
      mv[u] = make_float2(bf2f((unsigned short)(pk & 0xffffu)), bf2f((unsigned short)(pk >> 16)));
    }
    float q[8];
#pragma unroll
    for (int u = 0; u < 8; u++) {
      float e0 = mv[u].x + xri.x; e0 = fmaxf(e0, NSLOPE * e0);
      float e1 = mv[u].y + xri.y; e1 = fmaxf(e1, NSLOPE * e1);
      q[u] = (e + u < s1) ? fmaf(e0, at.x, e1 * at.y) : -1e30f;
    }
    // butterfly multi-reduce over the 16-lane head group: value index lands at lane&7
    float v0 = merge2(q[0], q[1], 1, lane);
    float v1 = merge2(q[2], q[3], 1, lane);
    float v2 = merge2(q[4], q[5], 1, lane);
    float v3 = merge2(q[6], q[7], 1, lane);
    float w0 = merge2(v0, v1, 2, lane);
    float w1 = merge2(v2, v3, 2, lane);
    float uu = merge2(w0, w1, 4, lane);
    uu += __shfl_xor(uu, 8);       // full 16-lane sum of q[lane&7]
    float p = __expf(uu);          // masked slots: exp(-1.6e31) = 0
    float cb[8];
#pragma unroll
    for (int u = 0; u < 8; u++) cb[u] = __shfl(p, base16 + u);
#pragma unroll
    for (int u = 0; u < 8; u++) {
      l += cb[u];
      a0 = fmaf(cb[u], mv[u].x, a0);
      a1 = fmaf(cb[u], mv[u].y, a1);
    }
  }
  float inv = 1.f / l;
  float2 bb = *(const float2*)(bias + c);
  float o0 = fmaxf(fmaf(a0, inv, bb.x), 0.f);
  float o1 = fmaxf(fmaf(a1, inv, bb.y), 0.f);
  *(float2*)(h + (size_t)node * 128 + c) = make_float2(o0, o1);
}

// edge2: one wave per dst node. 64 ch -> 1/lane, 1 head (64-wide reduce).
__global__ __launch_bounds__(256) void edge2_kernel(
    const float* __restrict__ xl, const float* __restrict__ xr,
    const float* __restrict__ att, const float* __restrict__ bias,
    const int* __restrict__ offsets, const int* __restrict__ csr_src,
    float* __restrict__ out, int N) {
  int node = blockIdx.x * 4 + (threadIdx.x >> 6);
  if (node >= N) return;
  int lane = threadIdx.x & 63;
  float xri = xr[(size_t)node * 64 + lane];
  float at  = att[lane];
  int s0 = __builtin_amdgcn_readfirstlane(offsets[node]);
  int s1 = __builtin_amdgcn_readfirstlane(offsets[node + 1]);
  int s1m1 = s1 - 1;
  float l = 0.f, a = 0.f;
  int base8 = lane & 56;  // start of this lane's 8-group
  for (int e = s0; e < s1; e += 8) {
    int j[8];
#pragma unroll
    for (int u = 0; u < 8; u++) {
      int ee = e + u;
      j[u] = __builtin_amdgcn_readfirstlane(csr_src[ee < s1 ? ee : s1m1]);
    }
    float mv[8];
#pragma unroll
    for (int u = 0; u < 8; u++) mv[u] = xl[(size_t)j[u] * 64 + lane];
    float q[8];
#pragma unroll
    for (int u = 0; u < 8; u++) {
      float ee = mv[u] + xri; ee = fmaxf(ee, NSLOPE * ee);
      q[u] = (e + u < s1) ? ee * at : -1e30f;
    }
    // butterfly multi-reduce across 64 lanes: value index lands at lane&7
    float v0 = merge2(q[0], q[1], 1, lane);
    float v1 = merge2(q[2], q[3], 1, lane);
    float v2 = merge2(q[4], q[5], 1, lane);
    float v3 = merge2(q[6], q[7], 1, lane);
    float w0 = merge2(v0, v1, 2, lane);
    float w1 = merge2(v2, v3, 2, lane);
    float uu = merge2(w0, w1, 4, lane);
    uu += __shfl_xor(uu, 8);
    uu += __shfl_xor(uu, 16);
    uu += __shfl_xor(uu, 32);      // full 64-lane sum of q[lane&7]
    float p = __expf(uu);
    float cb[8];
#pragma unroll
    for (int u = 0; u < 8; u++) cb[u] = __shfl(p, base8 + u);
#pragma unroll
    for (int u = 0; u < 8; u++) {
      l += cb[u];
      a = fmaf(cb[u], mv[u], a);
    }
  }
  out[(size_t)node * 64 + lane] = fmaf(a, 1.f / l, bias[lane]);
}

extern "C" void kernel_launch(void* const* d_in, const int* in_sizes, int n_in,
                              void* d_out, int out_size, void* d_ws, size_t ws_size,
                              hipStream_t stream) {
  const float* x    = (const float*)d_in[0];
  const int*   ei   = (const int*)d_in[1];
  const float* Wl1  = (const float*)d_in[2];
  const float* bl1  = (const float*)d_in[3];
  const float* Wr1  = (const float*)d_in[4];
  const float* br1  = (const float*)d_in[5];
  const float* att1 = (const float*)d_in[6];
  const float* bias1= (const float*)d_in[7];
  const float* Wl2  = (const float*)d_in[8];
  const float* bl2  = (const float*)d_in[9];
  const float* Wr2  = (const float*)d_in[10];
  const float* br2  = (const float*)d_in[11];
  const float* att2 = (const float*)d_in[12];
  const float* bias2= (const float*)d_in[13];
  float* out = (float*)d_out;

  const int N = in_sizes[0] / 128;
  const int E = in_sizes[1] / 2;
  const int Etot = E + N;
  const int* srcv = ei;
  const int* dstv = ei + E;

  char* ws = (char*)d_ws;
  size_t off = 0;
  auto alloc = [&](size_t bytes) -> void* {
    void* p = ws + off;
    off = (off + bytes + 255) & ~(size_t)255;
    return p;
  };
  int* offsets     = (int*)alloc((size_t)(N + 1) * 4);
  int* cursor      = (int*)alloc((size_t)N * 4);
  int* counts      = (int*)alloc((size_t)N * 4);
  int* blockSums   = (int*)alloc(256 * 4);
  int* blockPrefix = (int*)alloc(256 * 4);
  int* csr_src     = (int*)alloc((size_t)Etot * 4);
  unsigned short* B1hi = (unsigned short*)alloc(16 * 4 * 64 * 8 * 2);
  unsigned short* B1lo = (unsigned short*)alloc(16 * 4 * 64 * 8 * 2);
  unsigned short* B2hi = (unsigned short*)alloc(8 * 4 * 64 * 8 * 2);
  unsigned short* B2lo = (unsigned short*)alloc(8 * 4 * 64 * 8 * 2);
  unsigned short* xl1b = (unsigned short*)alloc((size_t)N * 128 * 2);  // bf16 xl1
  float* xr1 = (float*)alloc((size_t)N * 128 * 4);
  float* hbuf= (float*)alloc((size_t)N * 128 * 4);
  float* xl2 = xr1;             // reuse xr1's buffer (dead after edge1): N*64 f32
  float* xr2 = xr1 + (size_t)N * 64;
  (void)ws_size; (void)n_in; (void)out_size;

  int nb = (N + 1023) / 1024;
  int mb = (N + 127) / 128;

  hipMemsetAsync(counts, 0, (size_t)N * 4, stream);
  count_kernel<<<(E / 8 + 255) / 256, 256, 0, stream>>>(dstv, counts, E);
  scanA_kernel<<<nb, 256, 0, stream>>>(counts, offsets, blockSums, N);
  scanB_kernel<<<1, 64, 0, stream>>>(blockSums, blockPrefix, offsets, nb, N);
  scanC_kernel<<<(N + 255) / 256, 256, 0, stream>>>(blockPrefix, counts, offsets, cursor, csr_src, N);
  scatter_kernel<<<(E / 8 + 255) / 256, 256, 0, stream>>>(srcv, dstv, cursor, csr_src, E);

  prep_b_kernel<<<16, 256, 0, stream>>>(Wl1, Wr1, 128, B1hi, B1lo, 16 * 4 * 64);
  prep_b_kernel<<<8, 256, 0, stream>>>(Wl2, Wr2, 64, B2hi, B2lo, 8 * 4 * 64);

  gemm_mfma_kernel<true><<<dim3(mb, 4), 256, 0, stream>>>(x, B1hi, B1lo, bl1, br1, xl1b, xr1, 128, N);
  edge1_kernel<<<(N + 3) / 4, 256, 0, stream>>>(xl1b, xr1, att1, bias1, offsets, csr_src, hbuf, N);
  gemm_mfma_kernel<false><<<dim3(mb, 2), 256, 0, stream>>>(hbuf, B2hi, B2lo, bl2, br2, xl2, xr2, 64, N);
  edge2_kernel<<<(N + 3) / 4, 256, 0, stream>>>(xl2, xr2, att2, bias2, offsets, csr_src, out, N);
}

// Round 7
// 276.309 us; speedup vs baseline: 1.6005x; 1.1171x over previous
//
#include <hip/hip_runtime.h>
#include <hip/hip_bf16.h>
#include <math.h>

// GATv2 x2 layers. N=50000, E=800000 (+N self loops), D_in=128, H=4, Hd=32 (HC=128), D_out=64.
// R2: GEMMs -> bf16x3 split MFMA, W pre-swizzled to fragment layout.
// R3: no-max-shift softmax (scores tiny; shift-invariant), self-loop slot via scanC.
// R5: butterfly multi-reduce in edge kernels.
// R6: xl gathered at 16-bit, masked tail group (no serial remainder).
// R7: xl stored as f16 (better mantissa than bf16) + packed f16 score path with
//     v_dot2_f32_f16; edge2 processes 2 edges/wave-slot (halved bytes + DS/edge);
//     scatter made atomic-free (count_kernel emits per-edge rank).

#define NSLOPE 0.2f

typedef __attribute__((ext_vector_type(8))) short short8;
typedef __attribute__((ext_vector_type(4))) float f32x4;
typedef _Float16 h16x2 __attribute__((ext_vector_type(2)));

__device__ inline unsigned short f2bf(float f) {
  unsigned int u = __float_as_uint(f);
  u += 0x7fff + ((u >> 16) & 1);   // round-to-nearest-even
  return (unsigned short)(u >> 16);
}
__device__ inline float bf2f(unsigned short h) {
  return __uint_as_float(((unsigned int)h) << 16);
}

// butterfly pair-merge: result(l) = sum over {l, l^m} of (l&m ? qb : qa)
__device__ inline float merge2(float qa, float qb, int m, int lane) {
  bool hi = (lane & m) != 0;
  float sel = hi ? qb : qa;
  float oth = hi ? qa : qb;
  return sel + __shfl_xor(oth, m);
}

// ---------------- CSR build ----------------

// counts += 1 per edge; rank[e] = this edge's arrival index within its dst segment.
__global__ void count_kernel(const int* __restrict__ dst, int* __restrict__ counts,
                             int* __restrict__ rank, int E) {
  int base = blockIdx.x * 2048 + threadIdx.x;
  int d[8], r[8];
#pragma unroll
  for (int u = 0; u < 8; u++) {
    int idx = base + u * 256;
    d[u] = (idx < E) ? dst[idx] : -1;
  }
#pragma unroll
  for (int u = 0; u < 8; u++)
    if (d[u] >= 0) r[u] = atomicAdd(&counts[d[u]], 1);
#pragma unroll
  for (int u = 0; u < 8; u++) {
    int idx = base + u * 256;
    if (idx < E) rank[idx] = r[u];
  }
}

__global__ __launch_bounds__(256) void scanA_kernel(const int* __restrict__ counts,
                                                    int* __restrict__ offsets,
                                                    int* __restrict__ blockSums, int N) {
  int t = threadIdx.x;
  int lane = t & 63, wv = t >> 6;
  int g0 = blockIdx.x * 1024 + t * 4;
  int v[4];
#pragma unroll
  for (int u = 0; u < 4; u++) {
    int i = g0 + u;
    v[u] = (i < N) ? (counts[i] + 1) : 0;
  }
  int s = v[0] + v[1] + v[2] + v[3];
  int inc = s;
#pragma unroll
  for (int d = 1; d < 64; d <<= 1) {
    int n = __shfl_up(inc, d);
    if (lane >= d) inc += n;
  }
  __shared__ int wsum[4];
  if (lane == 63) wsum[wv] = inc;
  __syncthreads();
  int wprefix = 0;
#pragma unroll
  for (int w = 0; w < 4; w++)
    if (w < wv) wprefix += wsum[w];
  int run = wprefix + inc - s;
#pragma unroll
  for (int u = 0; u < 4; u++) {
    int i = g0 + u;
    if (i < N) offsets[i] = run;
    run += v[u];
  }
  if (t == 255) blockSums[blockIdx.x] = wprefix + inc;
}

__global__ void scanB_kernel(const int* __restrict__ blockSums, int* __restrict__ blockPrefix,
                             int* __restrict__ offsets, int nb, int N) {
  int lane = threadIdx.x;  // 64 threads
  int carry = 0;
  for (int base = 0; base < nb; base += 64) {
    int i = base + lane;
    int v = (i < nb) ? blockSums[i] : 0;
    int inc = v;
#pragma unroll
    for (int d = 1; d < 64; d <<= 1) {
      int n = __shfl_up(inc, d);
      if (lane >= d) inc += n;
    }
    if (i < nb) blockPrefix[i] = carry + inc - v;
    carry += __shfl(inc, 63);
  }
  if (lane == 0) offsets[N] = carry;
}

__global__ void scanC_kernel(const int* __restrict__ blockPrefix, const int* __restrict__ counts,
                             int* __restrict__ offsets, int* __restrict__ csr_src, int N) {
  int i = blockIdx.x * 256 + threadIdx.x;
  if (i < N) {
    int v = offsets[i] + blockPrefix[i >> 10];
    offsets[i] = v;
    csr_src[v + counts[i]] = i;  // self loop occupies the segment's last slot
  }
}

// atomic-free: position = offsets[dst] + rank (computed during count).
__global__ void scatter_kernel(const int* __restrict__ srcv, const int* __restrict__ dstv,
                               const int* __restrict__ offsets, const int* __restrict__ rank,
                               int* __restrict__ csr_src, int E) {
  int base = blockIdx.x * 2048 + threadIdx.x;
  int d[8], s[8], r[8];
#pragma unroll
  for (int u = 0; u < 8; u++) {
    int idx = base + u * 256;
    if (idx < E) { d[u] = dstv[idx]; s[u] = srcv[idx]; r[u] = rank[idx]; }
    else d[u] = -1;
  }
  int o[8];
#pragma unroll
  for (int u = 0; u < 8; u++)
    if (d[u] >= 0) o[u] = offsets[d[u]];
#pragma unroll
  for (int u = 0; u < 8; u++)
    if (d[u] >= 0) csr_src[o[u] + r[u]] = s[u];
}

// ---------------- MFMA GEMM (bf16x3 split) ----------------

__global__ __launch_bounds__(256) void prep_b_kernel(const float* __restrict__ Wl,
    const float* __restrict__ Wr, int C,
    unsigned short* __restrict__ Bhi, unsigned short* __restrict__ Blo, int total) {
  int t = blockIdx.x * 256 + threadIdx.x;
  if (t >= total) return;
  int lane = t & 63;
  int kt = (t >> 6) & 3;
  int tn = t >> 8;
  int n = tn * 16 + (lane & 15);
  int k0 = kt * 32 + ((lane >> 4) * 8);
  const float* W = (n < C) ? (Wl + n) : (Wr + (n - C));
  size_t base = ((size_t)(tn * 4 + kt) * 64 + lane) * 8;
#pragma unroll
  for (int j = 0; j < 8; j++) {
    float v = W[(size_t)(k0 + j) * C];
    unsigned short hi = f2bf(v);
    Bhi[base + j] = hi;
    Blo[base + j] = f2bf(v - bf2f(hi));
  }
}

// xl stored as f16 (for edge gathers), xr as f32.
__global__ __launch_bounds__(256) void gemm_mfma_kernel(const float* __restrict__ A,
    const unsigned short* __restrict__ Bhi, const unsigned short* __restrict__ Blo,
    const float* __restrict__ bl, const float* __restrict__ br,
    _Float16* __restrict__ xl, float* __restrict__ xr, int C, int M) {
  __shared__ unsigned short sBh[16 * 512];
  __shared__ unsigned short sBl[16 * 512];
  int t = threadIdx.x;
  int g = blockIdx.y;
  {
    const float4* srcH = (const float4*)(Bhi + (size_t)g * 8192);
    const float4* srcL = (const float4*)(Blo + (size_t)g * 8192);
    float4* dH = (float4*)sBh;
    float4* dL = (float4*)sBl;
#pragma unroll
    for (int i = 0; i < 4; i++) {
      dH[t + 256 * i] = srcH[t + 256 * i];
      dL[t + 256 * i] = srcL[t + 256 * i];
    }
  }
  __syncthreads();
  int w = t >> 6, l = t & 63;
  int m_base = blockIdx.x * 128 + w * 32;
  int mrow = l & 15;
  int kq = l >> 4;
  f32x4 acc[2][4];
#pragma unroll
  for (int mt = 0; mt < 2; mt++)
#pragma unroll
    for (int tn = 0; tn < 4; tn++) acc[mt][tn] = (f32x4){0.f, 0.f, 0.f, 0.f};

#pragma unroll
  for (int kt = 0; kt < 4; kt++) {
    short8 ah[2], al[2];
#pragma unroll
    for (int mt = 0; mt < 2; mt++) {
      int m = m_base + mt * 16 + mrow;
      m = (m < M) ? m : (M - 1);
      const float* pa = A + (size_t)m * 128 + kt * 32 + kq * 8;
      float4 v0 = *(const float4*)pa;
      float4 v1 = *(const float4*)(pa + 4);
      float f[8] = {v0.x, v0.y, v0.z, v0.w, v1.x, v1.y, v1.z, v1.w};
#pragma unroll
      for (int j = 0; j < 8; j++) {
        unsigned short hi = f2bf(f[j]);
        ah[mt][j] = (short)hi;
        al[mt][j] = (short)f2bf(f[j] - bf2f(hi));
      }
    }
#pragma unroll
    for (int tn = 0; tn < 4; tn++) {
      int off = ((tn * 4 + kt) * 64 + l) * 8;
      short8 bh = *(const short8*)(sBh + off);
      short8 blo = *(const short8*)(sBl + off);
#pragma unroll
      for (int mt = 0; mt < 2; mt++) {
        acc[mt][tn] = __builtin_amdgcn_mfma_f32_16x16x32_bf16(ah[mt], bh, acc[mt][tn], 0, 0, 0);
        acc[mt][tn] = __builtin_amdgcn_mfma_f32_16x16x32_bf16(ah[mt], blo, acc[mt][tn], 0, 0, 0);
        acc[mt][tn] = __builtin_amdgcn_mfma_f32_16x16x32_bf16(al[mt], bh, acc[mt][tn], 0, 0, 0);
      }
    }
  }
#pragma unroll
  for (int tn = 0; tn < 4; tn++) {
    int n = g * 64 + tn * 16 + mrow;
    float bias = (n < C) ? bl[n] : br[n - C];
#pragma unroll
    for (int mt = 0; mt < 2; mt++) {
#pragma unroll
      for (int r = 0; r < 4; r++) {
        int m = m_base + mt * 16 + kq * 4 + r;
        if (m < M) {
          float v = acc[mt][tn][r] + bias;
          if (n < C) xl[(size_t)m * C + n] = (_Float16)v;
          else       xr[(size_t)m * C + (n - C)] = v;
        }
      }
    }
  }
}

// ---------------- edge kernels ----------------

__device__ inline h16x2 leaky_pk(h16x2 s) {
  h16x2 s2 = s * (h16x2){(_Float16)NSLOPE, (_Float16)NSLOPE};
  return __builtin_elementwise_max(s, s2);
}

// edge1: one wave per dst node. 128 ch -> 2/lane (f16 gather, pk math + dot2).
__global__ __launch_bounds__(256) void edge1_kernel(
    const _Float16* __restrict__ xl, const float* __restrict__ xr,
    const float* __restrict__ att, const float* __restrict__ bias,
    const int* __restrict__ offsets, const int* __restrict__ csr_src,
    float* __restrict__ h, int N) {
  int node = blockIdx.x * 4 + (threadIdx.x >> 6);
  if (node >= N) return;
  int lane = threadIdx.x & 63;
  int c = lane * 2;
  float2 xrf = *(const float2*)(xr + (size_t)node * 128 + c);
  h16x2 xri = {(_Float16)xrf.x, (_Float16)xrf.y};
  float2 atf = *(const float2*)(att + c);
  h16x2 at = {(_Float16)atf.x, (_Float16)atf.y};
  int s0 = __builtin_amdgcn_readfirstlane(offsets[node]);
  int s1 = __builtin_amdgcn_readfirstlane(offsets[node + 1]);
  int s1m1 = s1 - 1;
  float l = 0.f, a0 = 0.f, a1 = 0.f;
  int base16 = lane & 48;
  for (int e = s0; e < s1; e += 8) {
    int j[8];
#pragma unroll
    for (int u = 0; u < 8; u++) {
      int ee = e + u;
      j[u] = __builtin_amdgcn_readfirstlane(csr_src[ee < s1 ? ee : s1m1]);
    }
    h16x2 mv[8];
#pragma unroll
    for (int u = 0; u < 8; u++) mv[u] = *(const h16x2*)(xl + (size_t)j[u] * 128 + c);
    float q[8];
#pragma unroll
    for (int u = 0; u < 8; u++) {
      h16x2 lk = leaky_pk(mv[u] + xri);
      q[u] = __builtin_amdgcn_fdot2(lk, at, (e + u < s1) ? 0.f : -1e30f, false);
    }
    float v0 = merge2(q[0], q[1], 1, lane);
    float v1 = merge2(q[2], q[3], 1, lane);
    float v2 = merge2(q[4], q[5], 1, lane);
    float v3 = merge2(q[6], q[7], 1, lane);
    float w0 = merge2(v0, v1, 2, lane);
    float w1 = merge2(v2, v3, 2, lane);
    float uu = merge2(w0, w1, 4, lane);
    uu += __shfl_xor(uu, 8);       // full 16-lane (head) sum of q[lane&7]
    float p = __expf(uu);          // masked slots -> 0
    float cb[8];
#pragma unroll
    for (int u = 0; u < 8; u++) cb[u] = __shfl(p, base16 + u);
#pragma unroll
    for (int u = 0; u < 8; u++) {
      l += cb[u];
      a0 = fmaf(cb[u], (float)mv[u].x, a0);
      a1 = fmaf(cb[u], (float)mv[u].y, a1);
    }
  }
  float inv = 1.f / l;
  float2 bb = *(const float2*)(bias + c);
  float o0 = fmaxf(fmaf(a0, inv, bb.x), 0.f);
  float o1 = fmaxf(fmaf(a1, inv, bb.y), 0.f);
  *(float2*)(h + (size_t)node * 128 + c) = make_float2(o0, o1);
}

// edge2: one wave per dst node, 2 edges per slot: half-wave (32 lanes) x 2 ch/lane f16.
__global__ __launch_bounds__(256) void edge2_kernel(
    const _Float16* __restrict__ xl, const float* __restrict__ xr,
    const float* __restrict__ att, const float* __restrict__ bias,
    const int* __restrict__ offsets, const int* __restrict__ csr_src,
    float* __restrict__ out, int N) {
  int node = blockIdx.x * 4 + (threadIdx.x >> 6);
  if (node >= N) return;
  int lane = threadIdx.x & 63;
  int half = lane >> 5;          // which edge of the pair
  int c = (lane & 31) * 2;       // channel pair
  float2 xrf = *(const float2*)(xr + (size_t)node * 64 + c);
  h16x2 xri = {(_Float16)xrf.x, (_Float16)xrf.y};
  float2 atf = *(const float2*)(att + c);
  h16x2 at = {(_Float16)atf.x, (_Float16)atf.y};
  int s0 = __builtin_amdgcn_readfirstlane(offsets[node]);
  int s1 = __builtin_amdgcn_readfirstlane(offsets[node + 1]);
  int s1m1 = s1 - 1;
  float l = 0.f, a0 = 0.f, a1 = 0.f;
  int hbase = lane & 32;
  for (int e = s0; e < s1; e += 16) {
    int j[8];
#pragma unroll
    for (int u = 0; u < 8; u++) {
      int ee = e + 2 * u + half;
      j[u] = csr_src[ee < s1 ? ee : s1m1];   // uniform within half-wave
    }
    h16x2 mv[8];
#pragma unroll
    for (int u = 0; u < 8; u++) mv[u] = *(const h16x2*)(xl + (size_t)j[u] * 64 + c);
    float q[8];
#pragma unroll
    for (int u = 0; u < 8; u++) {
      h16x2 lk = leaky_pk(mv[u] + xri);
      q[u] = __builtin_amdgcn_fdot2(lk, at, (e + 2 * u + half < s1) ? 0.f : -1e30f, false);
    }
    float v0 = merge2(q[0], q[1], 1, lane);
    float v1 = merge2(q[2], q[3], 1, lane);
    float v2 = merge2(q[4], q[5], 1, lane);
    float v3 = merge2(q[6], q[7], 1, lane);
    float w0 = merge2(v0, v1, 2, lane);
    float w1 = merge2(v2, v3, 2, lane);
    float uu = merge2(w0, w1, 4, lane);
    uu += __shfl_xor(uu, 8);
    uu += __shfl_xor(uu, 16);      // 32-lane (own half) sum of q[lane&7]
    float p = __expf(uu);
    float cb[8];
#pragma unroll
    for (int u = 0; u < 8; u++) cb[u] = __shfl(p, hbase + u);
#pragma unroll
    for (int u = 0; u < 8; u++) {
      l += cb[u];
      a0 = fmaf(cb[u], (float)mv[u].x, a0);
      a1 = fmaf(cb[u], (float)mv[u].y, a1);
    }
  }
  // combine the two halves (different edges, same channels)
  l  += __shfl_xor(l, 32);
  a0 += __shfl_xor(a0, 32);
  a1 += __shfl_xor(a1, 32);
  if (half == 0) {
    float inv = 1.f / l;
    float2 bb = *(const float2*)(bias + c);
    *(float2*)(out + (size_t)node * 64 + c) =
        make_float2(fmaf(a0, inv, bb.x), fmaf(a1, inv, bb.y));
  }
}

extern "C" void kernel_launch(void* const* d_in, const int* in_sizes, int n_in,
                              void* d_out, int out_size, void* d_ws, size_t ws_size,
                              hipStream_t stream) {
  const float* x    = (const float*)d_in[0];
  const int*   ei   = (const int*)d_in[1];
  const float* Wl1  = (const float*)d_in[2];
  const float* bl1  = (const float*)d_in[3];
  const float* Wr1  = (const float*)d_in[4];
  const float* br1  = (const float*)d_in[5];
  const float* att1 = (const float*)d_in[6];
  const float* bias1= (const float*)d_in[7];
  const float* Wl2  = (const float*)d_in[8];
  const float* bl2  = (const float*)d_in[9];
  const float* Wr2  = (const float*)d_in[10];
  const float* br2  = (const float*)d_in[11];
  const float* att2 = (const float*)d_in[12];
  const float* bias2= (const float*)d_in[13];
  float* out = (float*)d_out;

  const int N = in_sizes[0] / 128;
  const int E = in_sizes[1] / 2;
  const int Etot = E + N;
  const int* srcv = ei;
  const int* dstv = ei + E;

  char* ws = (char*)d_ws;
  size_t off = 0;
  auto alloc = [&](size_t bytes) -> void* {
    void* p = ws + off;
    off = (off + bytes + 255) & ~(size_t)255;
    return p;
  };
  int* offsets     = (int*)alloc((size_t)(N + 1) * 4);
  int* counts      = (int*)alloc((size_t)N * 4);
  int* blockSums   = (int*)alloc(256 * 4);
  int* blockPrefix = (int*)alloc(256 * 4);
  int* csr_src     = (int*)alloc((size_t)Etot * 4);
  int* rank        = (int*)alloc((size_t)E * 4);
  unsigned short* B1hi = (unsigned short*)alloc(16 * 4 * 64 * 8 * 2);
  unsigned short* B1lo = (unsigned short*)alloc(16 * 4 * 64 * 8 * 2);
  unsigned short* B2hi = (unsigned short*)alloc(8 * 4 * 64 * 8 * 2);
  unsigned short* B2lo = (unsigned short*)alloc(8 * 4 * 64 * 8 * 2);
  _Float16* xl1h = (_Float16*)alloc((size_t)N * 128 * 2);
  float* xr1 = (float*)alloc((size_t)N * 128 * 4);
  float* hbuf= (float*)alloc((size_t)N * 128 * 4);
  _Float16* xl2h = xl1h;          // reuse (dead after edge1): N*64 f16 fits
  float* xr2 = xr1;               // reuse (dead after edge1): N*64 f32 fits
  (void)ws_size; (void)n_in; (void)out_size;

  int nb = (N + 1023) / 1024;
  int mb = (N + 127) / 128;

  hipMemsetAsync(counts, 0, (size_t)N * 4, stream);
  count_kernel<<<(E + 2047) / 2048, 256, 0, stream>>>(dstv, counts, rank, E);
  scanA_kernel<<<nb, 256, 0, stream>>>(counts, offsets, blockSums, N);
  scanB_kernel<<<1, 64, 0, stream>>>(blockSums, blockPrefix, offsets, nb, N);
  scanC_kernel<<<(N + 255) / 256, 256, 0, stream>>>(blockPrefix, counts, offsets, csr_src, N);
  scatter_kernel<<<(E + 2047) / 2048, 256, 0, stream>>>(srcv, dstv, offsets, rank, csr_src, E);

  prep_b_kernel<<<16, 256, 0, stream>>>(Wl1, Wr1, 128, B1hi, B1lo, 16 * 4 * 64);
  prep_b_kernel<<<8, 256, 0, stream>>>(Wl2, Wr2, 64, B2hi, B2lo, 8 * 4 * 64);

  gemm_mfma_kernel<<<dim3(mb, 4), 256, 0, stream>>>(x, B1hi, B1lo, bl1, br1, xl1h, xr1, 128, N);
  edge1_kernel<<<(N + 3) / 4, 256, 0, stream>>>(xl1h, xr1, att1, bias1, offsets, csr_src, hbuf, N);
  gemm_mfma_kernel<<<dim3(mb, 2), 256, 0, stream>>>(hbuf, B2hi, B2lo, bl2, br2, xl2h, xr2, 64, N);
  edge2_kernel<<<(N + 3) / 4, 256, 0, stream>>>(xl2h, xr2, att2, bias2, offsets, csr_src, out, N);
}